// Round 1
// baseline (4375.760 us; speedup 1.0000x reference)
//
#include <hip/hip_runtime.h>
#include <math.h>

// Transformer block, fp32 baseline.
// D_MODEL=1024, N_HEAD=16, D_HEAD=64, EXP=4, B=2, T=2048, EPS=1e-5
// Pipeline: ln1 -> qkv gemm -> causal attn -> proj gemm (+x residual)
//           -> ln2 -> fc1 gemm (+exact gelu) -> fc2 gemm (+residual) -> out

#define D_MODEL 1024
#define N_HEAD  16
#define D_HEAD  64
#define SEQ_T   2048
#define BATCH   2
#define NROWS   (BATCH * SEQ_T)   // 4096
#define C3      (3 * D_MODEL)     // 3072
#define D_FF    (4 * D_MODEL)     // 4096

// ---------------------------------------------------------------- LayerNorm
__global__ __launch_bounds__(256) void ln_kernel(
    const float* __restrict__ in, const float* __restrict__ w,
    const float* __restrict__ b, float* __restrict__ out, int D)
{
    const int row = blockIdx.x;
    const int tid = threadIdx.x;
    const float* x = in + (size_t)row * D;

    float s = 0.f, s2 = 0.f;
    for (int i = tid; i < D; i += 256) {
        float v = x[i];
        s += v; s2 += v * v;
    }
    __shared__ float rs[256], rs2[256];
    rs[tid] = s; rs2[tid] = s2;
    __syncthreads();
    for (int off = 128; off > 0; off >>= 1) {
        if (tid < off) { rs[tid] += rs[tid + off]; rs2[tid] += rs2[tid + off]; }
        __syncthreads();
    }
    const float mu   = rs[0] / D;
    const float var  = rs2[0] / D - mu * mu;
    const float rstd = rsqrtf(var + 1e-5f);

    float* o = out + (size_t)row * D;
    for (int i = tid; i < D; i += 256)
        o[i] = (x[i] - mu) * rstd * w[i] + b[i];
}

// ------------------------------------------------------------------- GEMM
// C[M,N] = act(A[M,K] @ W[K,N] + bias[N]) (+ residual[M,N])
// BM=BN=128, BK=16, 256 threads, 8x8 micro-tile. All shapes divide evenly.
#define BM 128
#define BN 128
#define BK 16
#define TM 8
#define TN 8

__global__ __launch_bounds__(256) void gemm_kernel(
    const float* __restrict__ A, const float* __restrict__ W,
    const float* __restrict__ bias, const float* __restrict__ residual,
    float* __restrict__ C, int M, int N, int K, int act)
{
    __shared__ float As[BK][BM];       // transposed A tile: As[k][m]
    __shared__ float Bs[BK][BN + 4];   // +4 pad to break bank-conflict stride

    const int tid  = threadIdx.x;
    const int tx   = tid & 15;   // output col group
    const int ty   = tid >> 4;   // output row group
    const int row0 = blockIdx.y * BM;
    const int col0 = blockIdx.x * BN;

    float acc[TM][TN];
#pragma unroll
    for (int i = 0; i < TM; ++i)
#pragma unroll
        for (int j = 0; j < TN; ++j) acc[i][j] = 0.f;

    for (int k0 = 0; k0 < K; k0 += BK) {
#pragma unroll
        for (int i = 0; i < (BM * BK) / 256; ++i) {      // 8 loads
            int idx = tid + i * 256;
            int r = idx >> 4, c = idx & 15;              // r in [0,128), c in [0,16)
            As[c][r] = A[(size_t)(row0 + r) * K + k0 + c];
        }
#pragma unroll
        for (int i = 0; i < (BK * BN) / 256; ++i) {      // 8 loads
            int idx = tid + i * 256;
            int r = idx >> 7, c = idx & 127;             // r in [0,16), c in [0,128)
            Bs[r][c] = W[(size_t)(k0 + r) * N + col0 + c];
        }
        __syncthreads();

#pragma unroll
        for (int kk = 0; kk < BK; ++kk) {
            float a[TM], b[TN];
#pragma unroll
            for (int i = 0; i < TM; ++i) a[i] = As[kk][ty * TM + i];
#pragma unroll
            for (int j = 0; j < TN; ++j) b[j] = Bs[kk][tx * TN + j];
#pragma unroll
            for (int i = 0; i < TM; ++i)
#pragma unroll
                for (int j = 0; j < TN; ++j) acc[i][j] += a[i] * b[j];
        }
        __syncthreads();
    }

#pragma unroll
    for (int i = 0; i < TM; ++i) {
        const int r = row0 + ty * TM + i;
#pragma unroll
        for (int j = 0; j < TN; ++j) {
            const int c = col0 + tx * TN + j;
            float v = acc[i][j] + bias[c];
            if (act == 1)                       // exact GELU
                v = 0.5f * v * (1.0f + erff(v * 0.70710678118654752f));
            if (residual) v += residual[(size_t)r * N + c];
            C[(size_t)r * N + c] = v;
        }
    }
}

// ------------------------------------------------------------- Attention
// One wave (64 threads) per (b, h, q). Scores staged in LDS, two passes.
__global__ __launch_bounds__(64) void attn_kernel(
    const float* __restrict__ qkv, float* __restrict__ y)
{
    const int q    = blockIdx.x;
    const int h    = blockIdx.y;
    const int b    = blockIdx.z;
    const int lane = threadIdx.x;
    const float scale = 0.125f;   // 1/sqrt(64)

    __shared__ float sc[SEQ_T];
    __shared__ float qs[D_HEAD];

    const size_t rowq = ((size_t)b * SEQ_T + q) * C3;
    qs[lane] = qkv[rowq + h * D_HEAD + lane];
    __syncthreads();

    // pass 1: scores + max
    float m = -INFINITY;
    for (int j = lane; j <= q; j += 64) {
        const float* krow = qkv + ((size_t)b * SEQ_T + j) * C3 + D_MODEL + h * D_HEAD;
        float s = 0.f;
#pragma unroll
        for (int d = 0; d < D_HEAD; ++d) s += qs[d] * krow[d];
        s *= scale;
        sc[j] = s;
        m = fmaxf(m, s);
    }
#pragma unroll
    for (int off = 32; off > 0; off >>= 1) m = fmaxf(m, __shfl_down(m, off));
    m = __shfl(m, 0);

    // pass 2: exp + sum
    float sum = 0.f;
    for (int j = lane; j <= q; j += 64) {
        float p = __expf(sc[j] - m);
        sc[j] = p;
        sum += p;
    }
#pragma unroll
    for (int off = 32; off > 0; off >>= 1) sum += __shfl_down(sum, off);
    sum = __shfl(sum, 0);
    const float inv = 1.0f / sum;
    __syncthreads();

    // pass 3: weighted V sum; lane owns output dim `lane`
    float acc = 0.f;
    const float* vbase = qkv + (size_t)b * SEQ_T * C3 + 2 * D_MODEL + h * D_HEAD + lane;
    for (int j = 0; j <= q; ++j)
        acc += sc[j] * vbase[(size_t)j * C3];

    y[((size_t)b * SEQ_T + q) * D_MODEL + h * D_HEAD + lane] = acc * inv;
}

// ------------------------------------------------------------------ launch
extern "C" void kernel_launch(void* const* d_in, const int* in_sizes, int n_in,
                              void* d_out, int out_size, void* d_ws, size_t ws_size,
                              hipStream_t stream)
{
    const float* x      = (const float*)d_in[0];
    const float* ln1_w  = (const float*)d_in[1];
    const float* ln1_b  = (const float*)d_in[2];
    const float* attn_w = (const float*)d_in[3];
    const float* attn_b = (const float*)d_in[4];
    const float* proj_w = (const float*)d_in[5];
    const float* proj_b = (const float*)d_in[6];
    const float* ln2_w  = (const float*)d_in[7];
    const float* ln2_b  = (const float*)d_in[8];
    const float* fc_w   = (const float*)d_in[9];
    const float* fc_b   = (const float*)d_in[10];
    const float* fc2_w  = (const float*)d_in[11];
    const float* fc2_b  = (const float*)d_in[12];
    float* out = (float*)d_out;

    // ws layout (fp32):
    //   big    : max(4096*3072, 4096*4096) = 16M floats (qkv, later h)  @ 0
    //   ln_buf : 4M floats  @ 64MB
    //   y_buf  : 4M floats  @ 80MB
    //   xmid   : 4M floats  @ 96MB          (total 112MB)
    char* ws = (char*)d_ws;
    float* big    = (float*)(ws);
    float* ln_buf = (float*)(ws + (size_t)64 * 1024 * 1024);
    float* y_buf  = (float*)(ws + (size_t)80 * 1024 * 1024);
    float* xmid   = (float*)(ws + (size_t)96 * 1024 * 1024);

    dim3 blk256(256), blk64(64);

    // 1. ln1(x) -> ln_buf
    ln_kernel<<<dim3(NROWS), blk256, 0, stream>>>(x, ln1_w, ln1_b, ln_buf, D_MODEL);

    // 2. qkv = ln_buf @ attn_w + attn_b   [4096 x 3072]
    gemm_kernel<<<dim3(C3 / BN, NROWS / BM), blk256, 0, stream>>>(
        ln_buf, attn_w, attn_b, nullptr, big, NROWS, C3, D_MODEL, 0);

    // 3. attention -> y_buf [4096 x 1024]
    attn_kernel<<<dim3(SEQ_T, N_HEAD, BATCH), blk64, 0, stream>>>(big, y_buf);

    // 4. xmid = x + y_buf @ proj_w + proj_b
    gemm_kernel<<<dim3(D_MODEL / BN, NROWS / BM), blk256, 0, stream>>>(
        y_buf, proj_w, proj_b, x, xmid, NROWS, D_MODEL, D_MODEL, 0);

    // 5. ln2(xmid) -> ln_buf
    ln_kernel<<<dim3(NROWS), blk256, 0, stream>>>(xmid, ln2_w, ln2_b, ln_buf, D_MODEL);

    // 6. h = gelu(ln_buf @ fc_w + fc_b)   [4096 x 4096]
    gemm_kernel<<<dim3(D_FF / BN, NROWS / BM), blk256, 0, stream>>>(
        ln_buf, fc_w, fc_b, nullptr, big, NROWS, D_FF, D_MODEL, 1);

    // 7. out = xmid + big @ fc2_w + fc2_b [4096 x 1024]
    gemm_kernel<<<dim3(D_MODEL / BN, NROWS / BM), blk256, 0, stream>>>(
        big, fc2_w, fc2_b, xmid, out, NROWS, D_MODEL, D_FF, 0);
}

// Round 2
// 2241.870 us; speedup vs baseline: 1.9518x; 1.9518x over previous
//
#include <hip/hip_runtime.h>
#include <math.h>

// Transformer block, fp32. Round 2: flash-style tiled attention.
// D_MODEL=1024, N_HEAD=16, D_HEAD=64, EXP=4, B=2, T=2048, EPS=1e-5

#define D_MODEL 1024
#define N_HEAD  16
#define D_HEAD  64
#define SEQ_T   2048
#define BATCH   2
#define NROWS   (BATCH * SEQ_T)   // 4096
#define C3      (3 * D_MODEL)     // 3072
#define D_FF    (4 * D_MODEL)     // 4096

// ---------------------------------------------------------------- LayerNorm
__global__ __launch_bounds__(256) void ln_kernel(
    const float* __restrict__ in, const float* __restrict__ w,
    const float* __restrict__ b, float* __restrict__ out, int D)
{
    const int row = blockIdx.x;
    const int tid = threadIdx.x;
    const float* x = in + (size_t)row * D;

    float s = 0.f, s2 = 0.f;
    for (int i = tid; i < D; i += 256) {
        float v = x[i];
        s += v; s2 += v * v;
    }
    __shared__ float rs[256], rs2[256];
    rs[tid] = s; rs2[tid] = s2;
    __syncthreads();
    for (int off = 128; off > 0; off >>= 1) {
        if (tid < off) { rs[tid] += rs[tid + off]; rs2[tid] += rs2[tid + off]; }
        __syncthreads();
    }
    const float mu   = rs[0] / D;
    const float var  = rs2[0] / D - mu * mu;
    const float rstd = rsqrtf(var + 1e-5f);

    float* o = out + (size_t)row * D;
    for (int i = tid; i < D; i += 256)
        o[i] = (x[i] - mu) * rstd * w[i] + b[i];
}

// ------------------------------------------------------------------- GEMM
// C[M,N] = act(A[M,K] @ W[K,N] + bias[N]) (+ residual[M,N])
#define BM 128
#define BN 128
#define BK 16
#define TM 8
#define TN 8

__global__ __launch_bounds__(256) void gemm_kernel(
    const float* __restrict__ A, const float* __restrict__ W,
    const float* __restrict__ bias, const float* __restrict__ residual,
    float* __restrict__ C, int M, int N, int K, int act)
{
    __shared__ float As[BK][BM];
    __shared__ float Bs[BK][BN + 4];

    const int tid  = threadIdx.x;
    const int tx   = tid & 15;
    const int ty   = tid >> 4;
    const int row0 = blockIdx.y * BM;
    const int col0 = blockIdx.x * BN;

    float acc[TM][TN];
#pragma unroll
    for (int i = 0; i < TM; ++i)
#pragma unroll
        for (int j = 0; j < TN; ++j) acc[i][j] = 0.f;

    for (int k0 = 0; k0 < K; k0 += BK) {
#pragma unroll
        for (int i = 0; i < (BM * BK) / 256; ++i) {
            int idx = tid + i * 256;
            int r = idx >> 4, c = idx & 15;
            As[c][r] = A[(size_t)(row0 + r) * K + k0 + c];
        }
#pragma unroll
        for (int i = 0; i < (BK * BN) / 256; ++i) {
            int idx = tid + i * 256;
            int r = idx >> 7, c = idx & 127;
            Bs[r][c] = W[(size_t)(k0 + r) * N + col0 + c];
        }
        __syncthreads();

#pragma unroll
        for (int kk = 0; kk < BK; ++kk) {
            float a[TM], b[TN];
#pragma unroll
            for (int i = 0; i < TM; ++i) a[i] = As[kk][ty * TM + i];
#pragma unroll
            for (int j = 0; j < TN; ++j) b[j] = Bs[kk][tx * TN + j];
#pragma unroll
            for (int i = 0; i < TM; ++i)
#pragma unroll
                for (int j = 0; j < TN; ++j) acc[i][j] += a[i] * b[j];
        }
        __syncthreads();
    }

#pragma unroll
    for (int i = 0; i < TM; ++i) {
        const int r = row0 + ty * TM + i;
#pragma unroll
        for (int j = 0; j < TN; ++j) {
            const int c = col0 + tx * TN + j;
            float v = acc[i][j] + bias[c];
            if (act == 1)
                v = 0.5f * v * (1.0f + erff(v * 0.70710678118654752f));
            if (residual) v += residual[(size_t)r * N + c];
            C[(size_t)r * N + c] = v;
        }
    }
}

// ------------------------------------------------- Flash-style attention
// One 256-thread workgroup per (b, h, 64-row q-tile). K/V tiles staged in
// LDS; online softmax; 4x4 register micro-tile per thread.
// Thread map: tx = tid&15 (cols/dims), ty = tid>>4 (rows). Row stats are
// reduced across the 16 tx-lanes of a row group via shuffle-xor (lanes with
// the same ty are 16 consecutive lanes inside one wave).
#define AQ 64   // q rows per workgroup
#define AK 64   // k cols per tile
#define LDP 68  // LDS row stride (floats): 16B-aligned float4s, +4 bank shift

__global__ __launch_bounds__(256) void fattn_kernel(
    const float* __restrict__ qkv, float* __restrict__ y)
{
    const int qt   = gridDim.x - 1 - blockIdx.x;  // big tiles dispatched first
    const int h    = blockIdx.y;
    const int b    = blockIdx.z;
    const int tid  = threadIdx.x;
    const int tx   = tid & 15;
    const int ty   = tid >> 4;
    const int qbase = qt * AQ;
    const float scale = 0.125f;   // 1/sqrt(64)

    __shared__ float Qs[D_HEAD][LDP];  // [d][r]  (transposed)
    __shared__ float Ks[D_HEAD][LDP];  // [d][c]  (transposed)
    __shared__ float Vs[AK][LDP];      // [j][d]
    __shared__ float Ps[AK][LDP];      // [j][r]  (transposed)

    const size_t bT = (size_t)b * SEQ_T;
    const float* qptr = qkv + h * D_HEAD;
    const float* kptr = qkv + D_MODEL + h * D_HEAD;
    const float* vptr = qkv + 2 * D_MODEL + h * D_HEAD;

    // ---- load Q tile (transposed into LDS)
#pragma unroll
    for (int i = 0; i < 4; ++i) {
        int idx = tid + i * 256;            // 0..1023 float4 slots
        int r = idx >> 4, c4 = (idx & 15) * 4;
        const float4 v = *(const float4*)(qptr + (bT + qbase + r) * C3 + c4);
        Qs[c4 + 0][r] = v.x; Qs[c4 + 1][r] = v.y;
        Qs[c4 + 2][r] = v.z; Qs[c4 + 3][r] = v.w;
    }

    float m_run[4], l_run[4], acc[4][4];
#pragma unroll
    for (int i = 0; i < 4; ++i) {
        m_run[i] = -INFINITY; l_run[i] = 0.f;
#pragma unroll
        for (int j = 0; j < 4; ++j) acc[i][j] = 0.f;
    }

    const int ntiles = qt + 1;
    for (int t = 0; t < ntiles; ++t) {
        const int kb = t * AK;
        __syncthreads();   // prev PV done (and Q visible on t==0)

        // ---- load K (transposed) and V tiles
#pragma unroll
        for (int i = 0; i < 4; ++i) {
            int idx = tid + i * 256;
            int r = idx >> 4, c4 = (idx & 15) * 4;
            const float4 kv = *(const float4*)(kptr + (bT + kb + r) * C3 + c4);
            Ks[c4 + 0][r] = kv.x; Ks[c4 + 1][r] = kv.y;
            Ks[c4 + 2][r] = kv.z; Ks[c4 + 3][r] = kv.w;
            const float4 vv = *(const float4*)(vptr + (bT + kb + r) * C3 + c4);
            *(float4*)&Vs[r][c4] = vv;
        }
        __syncthreads();

        // ---- S = scale * Q K^T   (each thread 4 rows x 4 cols)
        float s[4][4] = {{0.f}};
#pragma unroll 8
        for (int d = 0; d < D_HEAD; ++d) {
            const float4 qv = *(const float4*)&Qs[d][ty * 4];
            const float4 kv = *(const float4*)&Ks[d][tx * 4];
            const float qa[4] = {qv.x, qv.y, qv.z, qv.w};
            const float ka[4] = {kv.x, kv.y, kv.z, kv.w};
#pragma unroll
            for (int i = 0; i < 4; ++i)
#pragma unroll
                for (int j = 0; j < 4; ++j) s[i][j] += qa[i] * ka[j];
        }

        const bool diag = (kb == qbase);
#pragma unroll
        for (int i = 0; i < 4; ++i) {
            const int r = ty * 4 + i;
#pragma unroll
            for (int j = 0; j < 4; ++j) {
                const int c = tx * 4 + j;
                float v = s[i][j] * scale;
                if (diag && c > r) v = -INFINITY;
                s[i][j] = v;
            }
        }

        // ---- online softmax stats (per row, reduce over 16 tx lanes)
        float alpha[4];
#pragma unroll
        for (int i = 0; i < 4; ++i) {
            float tmax = fmaxf(fmaxf(s[i][0], s[i][1]), fmaxf(s[i][2], s[i][3]));
            tmax = fmaxf(tmax, __shfl_xor(tmax, 1));
            tmax = fmaxf(tmax, __shfl_xor(tmax, 2));
            tmax = fmaxf(tmax, __shfl_xor(tmax, 4));
            tmax = fmaxf(tmax, __shfl_xor(tmax, 8));
            const float mnew = fmaxf(m_run[i], tmax);
            alpha[i] = __expf(m_run[i] - mnew);
            float psum = 0.f;
#pragma unroll
            for (int j = 0; j < 4; ++j) {
                const float p = __expf(s[i][j] - mnew);
                s[i][j] = p;
                psum += p;
            }
            psum += __shfl_xor(psum, 1);
            psum += __shfl_xor(psum, 2);
            psum += __shfl_xor(psum, 4);
            psum += __shfl_xor(psum, 8);
            l_run[i] = alpha[i] * l_run[i] + psum;
            m_run[i] = mnew;
#pragma unroll
            for (int j = 0; j < 4; ++j) acc[i][j] *= alpha[i];
        }

        // ---- store P transposed: Ps[c][r]
#pragma unroll
        for (int j = 0; j < 4; ++j) {
            float4 pc = make_float4(s[0][j], s[1][j], s[2][j], s[3][j]);
            *(float4*)&Ps[tx * 4 + j][ty * 4] = pc;
        }
        __syncthreads();

        // ---- O += P V
#pragma unroll 8
        for (int j = 0; j < AK; ++j) {
            const float4 pv = *(const float4*)&Ps[j][ty * 4];
            const float4 vv = *(const float4*)&Vs[j][tx * 4];
            const float pa[4] = {pv.x, pv.y, pv.z, pv.w};
            const float va[4] = {vv.x, vv.y, vv.z, vv.w};
#pragma unroll
            for (int i = 0; i < 4; ++i)
#pragma unroll
                for (int jj = 0; jj < 4; ++jj) acc[i][jj] += pa[i] * va[jj];
        }
    }

    // ---- write O / l
#pragma unroll
    for (int i = 0; i < 4; ++i) {
        const float inv = 1.0f / l_run[i];
        const int r = qbase + ty * 4 + i;
        float4 o = make_float4(acc[i][0] * inv, acc[i][1] * inv,
                               acc[i][2] * inv, acc[i][3] * inv);
        *(float4*)(y + (bT + r) * D_MODEL + h * D_HEAD + tx * 4) = o;
    }
}

// ------------------------------------------------------------------ launch
extern "C" void kernel_launch(void* const* d_in, const int* in_sizes, int n_in,
                              void* d_out, int out_size, void* d_ws, size_t ws_size,
                              hipStream_t stream)
{
    const float* x      = (const float*)d_in[0];
    const float* ln1_w  = (const float*)d_in[1];
    const float* ln1_b  = (const float*)d_in[2];
    const float* attn_w = (const float*)d_in[3];
    const float* attn_b = (const float*)d_in[4];
    const float* proj_w = (const float*)d_in[5];
    const float* proj_b = (const float*)d_in[6];
    const float* ln2_w  = (const float*)d_in[7];
    const float* ln2_b  = (const float*)d_in[8];
    const float* fc_w   = (const float*)d_in[9];
    const float* fc_b   = (const float*)d_in[10];
    const float* fc2_w  = (const float*)d_in[11];
    const float* fc2_b  = (const float*)d_in[12];
    float* out = (float*)d_out;

    char* ws = (char*)d_ws;
    float* big    = (float*)(ws);                              // 64MB: qkv / h
    float* ln_buf = (float*)(ws + (size_t)64 * 1024 * 1024);   // 16MB
    float* y_buf  = (float*)(ws + (size_t)80 * 1024 * 1024);   // 16MB
    float* xmid   = (float*)(ws + (size_t)96 * 1024 * 1024);   // 16MB

    dim3 blk256(256);

    // 1. ln1(x) -> ln_buf
    ln_kernel<<<dim3(NROWS), blk256, 0, stream>>>(x, ln1_w, ln1_b, ln_buf, D_MODEL);

    // 2. qkv = ln_buf @ attn_w + attn_b   [4096 x 3072]
    gemm_kernel<<<dim3(C3 / BN, NROWS / BM), blk256, 0, stream>>>(
        ln_buf, attn_w, attn_b, nullptr, big, NROWS, C3, D_MODEL, 0);

    // 3. attention -> y_buf [4096 x 1024]
    fattn_kernel<<<dim3(SEQ_T / AQ, N_HEAD, BATCH), blk256, 0, stream>>>(big, y_buf);

    // 4. xmid = x + y_buf @ proj_w + proj_b
    gemm_kernel<<<dim3(D_MODEL / BN, NROWS / BM), blk256, 0, stream>>>(
        y_buf, proj_w, proj_b, x, xmid, NROWS, D_MODEL, D_MODEL, 0);

    // 5. ln2(xmid) -> ln_buf
    ln_kernel<<<dim3(NROWS), blk256, 0, stream>>>(xmid, ln2_w, ln2_b, ln_buf, D_MODEL);

    // 6. h = gelu(ln_buf @ fc_w + fc_b)   [4096 x 4096]
    gemm_kernel<<<dim3(D_FF / BN, NROWS / BM), blk256, 0, stream>>>(
        ln_buf, fc_w, fc_b, nullptr, big, NROWS, D_FF, D_MODEL, 1);

    // 7. out = xmid + big @ fc2_w + fc2_b [4096 x 1024]
    gemm_kernel<<<dim3(D_MODEL / BN, NROWS / BM), blk256, 0, stream>>>(
        big, fc2_w, fc2_b, xmid, out, NROWS, D_MODEL, D_FF, 0);
}

// Round 3
// 927.649 us; speedup vs baseline: 4.7170x; 2.4167x over previous
//
#include <hip/hip_runtime.h>
#include <hip/hip_bf16.h>
#include <math.h>

// Transformer block. Round 3: bf16-MFMA GEMMs (m97 structure), fp32 attention.
// D_MODEL=1024, N_HEAD=16, D_HEAD=64, EXP=4, B=2, T=2048, EPS=1e-5

#define D_MODEL 1024
#define N_HEAD  16
#define D_HEAD  64
#define SEQ_T   2048
#define BATCH   2
#define NROWS   (BATCH * SEQ_T)   // 4096
#define C3      (3 * D_MODEL)     // 3072
#define D_FF    (4 * D_MODEL)     // 4096

typedef __bf16 bf16x8 __attribute__((ext_vector_type(8)));
typedef float  f32x4  __attribute__((ext_vector_type(4)));

// ---------------------------------------------------------------- LayerNorm
// fp32 in -> bf16 out
__global__ __launch_bounds__(256) void ln_kernel(
    const float* __restrict__ in, const float* __restrict__ w,
    const float* __restrict__ b, __hip_bfloat16* __restrict__ out, int D)
{
    const int row = blockIdx.x;
    const int tid = threadIdx.x;
    const float* x = in + (size_t)row * D;

    float s = 0.f, s2 = 0.f;
    for (int i = tid; i < D; i += 256) {
        float v = x[i];
        s += v; s2 += v * v;
    }
    __shared__ float rs[256], rs2[256];
    rs[tid] = s; rs2[tid] = s2;
    __syncthreads();
    for (int off = 128; off > 0; off >>= 1) {
        if (tid < off) { rs[tid] += rs[tid + off]; rs2[tid] += rs2[tid + off]; }
        __syncthreads();
    }
    const float mu   = rs[0] / D;
    const float var  = rs2[0] / D - mu * mu;
    const float rstd = rsqrtf(var + 1e-5f);

    __hip_bfloat16* o = out + (size_t)row * D;
    for (int i = tid; i < D; i += 256)
        o[i] = __float2bfloat16((x[i] - mu) * rstd * w[i] + b[i]);
}

// ------------------------------------------- weight transpose + bf16 cast
// W[K,N] fp32 -> Wt[N,K] bf16.  32x32 tiles, 256 threads (32x8).
__global__ __launch_bounds__(256) void transpose_bf16_kernel(
    const float* __restrict__ W, __hip_bfloat16* __restrict__ Wt, int K, int N)
{
    __shared__ float t[32][33];
    const int tx = threadIdx.x & 31;
    const int ty = threadIdx.x >> 5;     // 0..7
    const int k0 = blockIdx.y * 32;
    const int n0 = blockIdx.x * 32;
#pragma unroll
    for (int i = 0; i < 4; ++i)
        t[ty + 8 * i][tx] = W[(size_t)(k0 + ty + 8 * i) * N + n0 + tx];
    __syncthreads();
#pragma unroll
    for (int i = 0; i < 4; ++i)
        Wt[(size_t)(n0 + ty + 8 * i) * K + k0 + tx] =
            __float2bfloat16(t[tx][ty + 8 * i]);
}

// ----------------------------------------------------------- bf16 MFMA GEMM
// C[M,N] = act(A[M,K] @ Bt[N,K]^T + bias[N]) (+ residual)
// 128x128 tile, BK=32, 256 threads = 4 waves (2x2), each wave 64x64 via
// 4x4 grid of 16x16x32 MFMA tiles. global_load_lds width-16 staging.

__device__ __forceinline__ void async16(const __hip_bfloat16* g, __hip_bfloat16* l)
{
    __builtin_amdgcn_global_load_lds(
        (const __attribute__((address_space(1))) void*)g,
        (__attribute__((address_space(3))) void*)l, 16, 0, 0);
}

__device__ __forceinline__ float gelu_exact(float v)
{
    return 0.5f * v * (1.0f + erff(v * 0.70710678118654752f));
}

__global__ __launch_bounds__(256) void mfma_gemm_kernel(
    const __hip_bfloat16* __restrict__ A,   // [M,K]
    const __hip_bfloat16* __restrict__ Bt,  // [N,K]
    const float* __restrict__ bias,         // [N]
    const float* __restrict__ residual,     // [M,N] or null
    void* __restrict__ Cout,                // [M,N] fp32 or bf16
    int M, int N, int K, int act, int outBf16)
{
    __shared__ __align__(16) __hip_bfloat16 As[128 * 32];
    __shared__ __align__(16) __hip_bfloat16 Bs[128 * 32];

    const int tid  = threadIdx.x;
    const int wv   = tid >> 6;        // wave 0..3
    const int lane = tid & 63;
    const int ln15 = lane & 15;
    const int lq   = lane >> 4;       // 0..3
    const int wm   = (wv >> 1) * 64;  // wave row offset in tile
    const int wn   = (wv & 1) * 64;   // wave col offset in tile
    const int row0 = blockIdx.y * 128;
    const int col0 = blockIdx.x * 128;

    // staging map: lane covers row r = i*64 + wv*16 + lane/4, chunk q = lane&3
    const int sr = wv * 16 + (lane >> 2);
    const int sq = (lane & 3) * 8;

    f32x4 acc[4][4];
#pragma unroll
    for (int i = 0; i < 4; ++i)
#pragma unroll
        for (int j = 0; j < 4; ++j) acc[i][j] = (f32x4){0.f, 0.f, 0.f, 0.f};

    for (int k0 = 0; k0 < K; k0 += 32) {
        __syncthreads();   // previous iter's ds_reads complete
#pragma unroll
        for (int i = 0; i < 2; ++i) {
            const int r = i * 64 + sr;
            async16(A  + (size_t)(row0 + r) * K + k0 + sq, As + r * 32);
            async16(Bt + (size_t)(col0 + r) * K + k0 + sq, Bs + r * 32);
        }
        __syncthreads();   // staging complete (barrier drains vmcnt)

        bf16x8 af[4], bfr[4];
#pragma unroll
        for (int mi = 0; mi < 4; ++mi)
            af[mi] = *(const bf16x8*)&As[(wm + mi * 16 + ln15) * 32 + lq * 8];
#pragma unroll
        for (int ni = 0; ni < 4; ++ni)
            bfr[ni] = *(const bf16x8*)&Bs[(wn + ni * 16 + ln15) * 32 + lq * 8];
#pragma unroll
        for (int mi = 0; mi < 4; ++mi)
#pragma unroll
            for (int ni = 0; ni < 4; ++ni)
                acc[mi][ni] = __builtin_amdgcn_mfma_f32_16x16x32_bf16(
                    af[mi], bfr[ni], acc[mi][ni], 0, 0, 0);
    }

    // epilogue: C/D layout col=lane&15, row=(lane>>4)*4+reg  [m89/m91]
#pragma unroll
    for (int mi = 0; mi < 4; ++mi) {
#pragma unroll
        for (int ni = 0; ni < 4; ++ni) {
            const int gc = col0 + wn + ni * 16 + ln15;
            const float bv = bias[gc];
#pragma unroll
            for (int r = 0; r < 4; ++r) {
                const int gr = row0 + wm + mi * 16 + lq * 4 + r;
                float v = acc[mi][ni][r] + bv;
                if (act == 1) v = gelu_exact(v);
                if (residual) v += residual[(size_t)gr * N + gc];
                if (outBf16)
                    ((__hip_bfloat16*)Cout)[(size_t)gr * N + gc] = __float2bfloat16(v);
                else
                    ((float*)Cout)[(size_t)gr * N + gc] = v;
            }
        }
    }
}

// ------------------------------------------------- Flash-style attention
// fp32 qkv in, bf16 y out. One 256-thread workgroup per (b,h,64-row q-tile).
#define AQ 64
#define AK 64
#define LDP 68

__global__ __launch_bounds__(256) void fattn_kernel(
    const float* __restrict__ qkv, __hip_bfloat16* __restrict__ y)
{
    const int qt   = gridDim.x - 1 - blockIdx.x;
    const int h    = blockIdx.y;
    const int b    = blockIdx.z;
    const int tid  = threadIdx.x;
    const int tx   = tid & 15;
    const int ty   = tid >> 4;
    const int qbase = qt * AQ;
    const float scale = 0.125f;

    __shared__ float Qs[D_HEAD][LDP];
    __shared__ float Ks[D_HEAD][LDP];
    __shared__ float Vs[AK][LDP];
    __shared__ float Ps[AK][LDP];

    const size_t bT = (size_t)b * SEQ_T;
    const float* qptr = qkv + h * D_HEAD;
    const float* kptr = qkv + D_MODEL + h * D_HEAD;
    const float* vptr = qkv + 2 * D_MODEL + h * D_HEAD;

#pragma unroll
    for (int i = 0; i < 4; ++i) {
        int idx = tid + i * 256;
        int r = idx >> 4, c4 = (idx & 15) * 4;
        const float4 v = *(const float4*)(qptr + (bT + qbase + r) * C3 + c4);
        Qs[c4 + 0][r] = v.x; Qs[c4 + 1][r] = v.y;
        Qs[c4 + 2][r] = v.z; Qs[c4 + 3][r] = v.w;
    }

    float m_run[4], l_run[4], acc[4][4];
#pragma unroll
    for (int i = 0; i < 4; ++i) {
        m_run[i] = -INFINITY; l_run[i] = 0.f;
#pragma unroll
        for (int j = 0; j < 4; ++j) acc[i][j] = 0.f;
    }

    const int ntiles = qt + 1;
    for (int t = 0; t < ntiles; ++t) {
        const int kb = t * AK;
        __syncthreads();

#pragma unroll
        for (int i = 0; i < 4; ++i) {
            int idx = tid + i * 256;
            int r = idx >> 4, c4 = (idx & 15) * 4;
            const float4 kv = *(const float4*)(kptr + (bT + kb + r) * C3 + c4);
            Ks[c4 + 0][r] = kv.x; Ks[c4 + 1][r] = kv.y;
            Ks[c4 + 2][r] = kv.z; Ks[c4 + 3][r] = kv.w;
            const float4 vv = *(const float4*)(vptr + (bT + kb + r) * C3 + c4);
            *(float4*)&Vs[r][c4] = vv;
        }
        __syncthreads();

        float s[4][4] = {{0.f}};
#pragma unroll 8
        for (int d = 0; d < D_HEAD; ++d) {
            const float4 qv = *(const float4*)&Qs[d][ty * 4];
            const float4 kv = *(const float4*)&Ks[d][tx * 4];
            const float qa[4] = {qv.x, qv.y, qv.z, qv.w};
            const float ka[4] = {kv.x, kv.y, kv.z, kv.w};
#pragma unroll
            for (int i = 0; i < 4; ++i)
#pragma unroll
                for (int j = 0; j < 4; ++j) s[i][j] += qa[i] * ka[j];
        }

        const bool diag = (kb == qbase);
#pragma unroll
        for (int i = 0; i < 4; ++i) {
            const int r = ty * 4 + i;
#pragma unroll
            for (int j = 0; j < 4; ++j) {
                const int c = tx * 4 + j;
                float v = s[i][j] * scale;
                if (diag && c > r) v = -INFINITY;
                s[i][j] = v;
            }
        }

        float alpha[4];
#pragma unroll
        for (int i = 0; i < 4; ++i) {
            float tmax = fmaxf(fmaxf(s[i][0], s[i][1]), fmaxf(s[i][2], s[i][3]));
            tmax = fmaxf(tmax, __shfl_xor(tmax, 1));
            tmax = fmaxf(tmax, __shfl_xor(tmax, 2));
            tmax = fmaxf(tmax, __shfl_xor(tmax, 4));
            tmax = fmaxf(tmax, __shfl_xor(tmax, 8));
            const float mnew = fmaxf(m_run[i], tmax);
            alpha[i] = __expf(m_run[i] - mnew);
            float psum = 0.f;
#pragma unroll
            for (int j = 0; j < 4; ++j) {
                const float p = __expf(s[i][j] - mnew);
                s[i][j] = p;
                psum += p;
            }
            psum += __shfl_xor(psum, 1);
            psum += __shfl_xor(psum, 2);
            psum += __shfl_xor(psum, 4);
            psum += __shfl_xor(psum, 8);
            l_run[i] = alpha[i] * l_run[i] + psum;
            m_run[i] = mnew;
#pragma unroll
            for (int j = 0; j < 4; ++j) acc[i][j] *= alpha[i];
        }

#pragma unroll
        for (int j = 0; j < 4; ++j) {
            float4 pc = make_float4(s[0][j], s[1][j], s[2][j], s[3][j]);
            *(float4*)&Ps[tx * 4 + j][ty * 4] = pc;
        }
        __syncthreads();

#pragma unroll 8
        for (int j = 0; j < AK; ++j) {
            const float4 pv = *(const float4*)&Ps[j][ty * 4];
            const float4 vv = *(const float4*)&Vs[j][tx * 4];
            const float pa[4] = {pv.x, pv.y, pv.z, pv.w};
            const float va[4] = {vv.x, vv.y, vv.z, vv.w};
#pragma unroll
            for (int i = 0; i < 4; ++i)
#pragma unroll
                for (int jj = 0; jj < 4; ++jj) acc[i][jj] += pa[i] * va[jj];
        }
    }

#pragma unroll
    for (int i = 0; i < 4; ++i) {
        const float inv = 1.0f / l_run[i];
        const int r = qbase + ty * 4 + i;
        __hip_bfloat16* yo = y + (bT + r) * D_MODEL + h * D_HEAD + tx * 4;
#pragma unroll
        for (int j = 0; j < 4; ++j)
            yo[j] = __float2bfloat16(acc[i][j] * inv);
    }
}

// ------------------------------------------------------------------ launch
extern "C" void kernel_launch(void* const* d_in, const int* in_sizes, int n_in,
                              void* d_out, int out_size, void* d_ws, size_t ws_size,
                              hipStream_t stream)
{
    const float* x      = (const float*)d_in[0];
    const float* ln1_w  = (const float*)d_in[1];
    const float* ln1_b  = (const float*)d_in[2];
    const float* attn_w = (const float*)d_in[3];
    const float* attn_b = (const float*)d_in[4];
    const float* proj_w = (const float*)d_in[5];
    const float* proj_b = (const float*)d_in[6];
    const float* ln2_w  = (const float*)d_in[7];
    const float* ln2_b  = (const float*)d_in[8];
    const float* fc_w   = (const float*)d_in[9];
    const float* fc_b   = (const float*)d_in[10];
    const float* fc2_w  = (const float*)d_in[11];
    const float* fc2_b  = (const float*)d_in[12];
    float* out = (float*)d_out;

    // ws layout (bytes):
    //   big     @ 0    : qkv fp32 48MB, later h bf16 32MB
    //   ln_buf  @ 48M  : bf16 8MB
    //   y_buf   @ 56M  : bf16 8MB
    //   xmid    @ 64M  : fp32 16MB
    //   attn_wt @ 80M  : bf16 6MB   [3072,1024]
    //   proj_wt @ 86M  : bf16 2MB   [1024,1024]
    //   fc_wt   @ 88M  : bf16 8MB   [4096,1024]
    //   fc2_wt  @ 96M  : bf16 8MB   [1024,4096]   (total 104MB)
    char* ws = (char*)d_ws;
    float*           qkv_f   = (float*)(ws);
    __hip_bfloat16*  h_bf    = (__hip_bfloat16*)(ws);
    __hip_bfloat16*  ln_buf  = (__hip_bfloat16*)(ws + (size_t)48 * 1024 * 1024);
    __hip_bfloat16*  y_buf   = (__hip_bfloat16*)(ws + (size_t)56 * 1024 * 1024);
    float*           xmid    = (float*)(ws + (size_t)64 * 1024 * 1024);
    __hip_bfloat16*  attn_wt = (__hip_bfloat16*)(ws + (size_t)80 * 1024 * 1024);
    __hip_bfloat16*  proj_wt = (__hip_bfloat16*)(ws + (size_t)86 * 1024 * 1024);
    __hip_bfloat16*  fc_wt   = (__hip_bfloat16*)(ws + (size_t)88 * 1024 * 1024);
    __hip_bfloat16*  fc2_wt  = (__hip_bfloat16*)(ws + (size_t)96 * 1024 * 1024);

    dim3 blk256(256);

    // 0. weight transposes (fp32 [K,N] -> bf16 [N,K])
    transpose_bf16_kernel<<<dim3(C3 / 32, D_MODEL / 32), blk256, 0, stream>>>(
        attn_w, attn_wt, D_MODEL, C3);
    transpose_bf16_kernel<<<dim3(D_MODEL / 32, D_MODEL / 32), blk256, 0, stream>>>(
        proj_w, proj_wt, D_MODEL, D_MODEL);
    transpose_bf16_kernel<<<dim3(D_FF / 32, D_MODEL / 32), blk256, 0, stream>>>(
        fc_w, fc_wt, D_MODEL, D_FF);
    transpose_bf16_kernel<<<dim3(D_MODEL / 32, D_FF / 32), blk256, 0, stream>>>(
        fc2_w, fc2_wt, D_FF, D_MODEL);

    // 1. ln1(x) -> ln_buf (bf16)
    ln_kernel<<<dim3(NROWS), blk256, 0, stream>>>(x, ln1_w, ln1_b, ln_buf, D_MODEL);

    // 2. qkv = ln_buf @ attn_w + attn_b  -> fp32 [4096 x 3072]
    mfma_gemm_kernel<<<dim3(C3 / 128, NROWS / 128), blk256, 0, stream>>>(
        ln_buf, attn_wt, attn_b, nullptr, qkv_f, NROWS, C3, D_MODEL, 0, 0);

    // 3. attention -> y_buf (bf16) [4096 x 1024]
    fattn_kernel<<<dim3(SEQ_T / AQ, N_HEAD, BATCH), blk256, 0, stream>>>(qkv_f, y_buf);

    // 4. xmid = x + y_buf @ proj_w + proj_b  -> fp32
    mfma_gemm_kernel<<<dim3(D_MODEL / 128, NROWS / 128), blk256, 0, stream>>>(
        y_buf, proj_wt, proj_b, x, xmid, NROWS, D_MODEL, D_MODEL, 0, 0);

    // 5. ln2(xmid) -> ln_buf (bf16)
    ln_kernel<<<dim3(NROWS), blk256, 0, stream>>>(xmid, ln2_w, ln2_b, ln_buf, D_MODEL);

    // 6. h = gelu(ln_buf @ fc_w + fc_b) -> bf16 [4096 x 4096]
    mfma_gemm_kernel<<<dim3(D_FF / 128, NROWS / 128), blk256, 0, stream>>>(
        ln_buf, fc_wt, fc_b, nullptr, h_bf, NROWS, D_FF, D_MODEL, 1, 1);

    // 7. out = xmid + h @ fc2_w + fc2_b -> fp32 [4096 x 1024]
    mfma_gemm_kernel<<<dim3(D_MODEL / 128, NROWS / 128), blk256, 0, stream>>>(
        h_bf, fc2_wt, fc2_b, xmid, out, NROWS, D_MODEL, D_FF, 0, 0);
}

// Round 4
// 516.018 us; speedup vs baseline: 8.4799x; 1.7977x over previous
//
#include <hip/hip_runtime.h>
#include <hip/hip_bf16.h>
#include <math.h>

// Transformer block. Round 4: MFMA flash attention + fused qkv bf16 epilogue.
// D_MODEL=1024, N_HEAD=16, D_HEAD=64, EXP=4, B=2, T=2048, EPS=1e-5

#define D_MODEL 1024
#define N_HEAD  16
#define D_HEAD  64
#define SEQ_T   2048
#define BATCH   2
#define NROWS   (BATCH * SEQ_T)   // 4096
#define C3      (3 * D_MODEL)     // 3072
#define D_FF    (4 * D_MODEL)     // 4096

typedef __bf16 bf16x8 __attribute__((ext_vector_type(8)));
typedef float  f32x4  __attribute__((ext_vector_type(4)));

// ---------------------------------------------------------------- LayerNorm
__global__ __launch_bounds__(256) void ln_kernel(
    const float* __restrict__ in, const float* __restrict__ w,
    const float* __restrict__ b, __hip_bfloat16* __restrict__ out, int D)
{
    const int row = blockIdx.x;
    const int tid = threadIdx.x;
    const float* x = in + (size_t)row * D;

    float s = 0.f, s2 = 0.f;
    for (int i = tid; i < D; i += 256) {
        float v = x[i];
        s += v; s2 += v * v;
    }
    __shared__ float rs[256], rs2[256];
    rs[tid] = s; rs2[tid] = s2;
    __syncthreads();
    for (int off = 128; off > 0; off >>= 1) {
        if (tid < off) { rs[tid] += rs[tid + off]; rs2[tid] += rs2[tid + off]; }
        __syncthreads();
    }
    const float mu   = rs[0] / D;
    const float var  = rs2[0] / D - mu * mu;
    const float rstd = rsqrtf(var + 1e-5f);

    __hip_bfloat16* o = out + (size_t)row * D;
    for (int i = tid; i < D; i += 256)
        o[i] = __float2bfloat16((x[i] - mu) * rstd * w[i] + b[i]);
}

// ------------------------------------------- weight transpose + bf16 cast
__global__ __launch_bounds__(256) void transpose_bf16_kernel(
    const float* __restrict__ W, __hip_bfloat16* __restrict__ Wt, int K, int N)
{
    __shared__ float t[32][33];
    const int tx = threadIdx.x & 31;
    const int ty = threadIdx.x >> 5;
    const int k0 = blockIdx.y * 32;
    const int n0 = blockIdx.x * 32;
#pragma unroll
    for (int i = 0; i < 4; ++i)
        t[ty + 8 * i][tx] = W[(size_t)(k0 + ty + 8 * i) * N + n0 + tx];
    __syncthreads();
#pragma unroll
    for (int i = 0; i < 4; ++i)
        Wt[(size_t)(n0 + ty + 8 * i) * K + k0 + tx] =
            __float2bfloat16(t[tx][ty + 8 * i]);
}

// ----------------------------------------------------------- bf16 MFMA GEMM
__device__ __forceinline__ void async16(const __hip_bfloat16* g, __hip_bfloat16* l)
{
    __builtin_amdgcn_global_load_lds(
        (const __attribute__((address_space(1))) void*)g,
        (__attribute__((address_space(3))) void*)l, 16, 0, 0);
}

__device__ __forceinline__ float gelu_exact(float v)
{
    return 0.5f * v * (1.0f + erff(v * 0.70710678118654752f));
}

__global__ __launch_bounds__(256) void mfma_gemm_kernel(
    const __hip_bfloat16* __restrict__ A,   // [M,K]
    const __hip_bfloat16* __restrict__ Bt,  // [N,K]
    const float* __restrict__ bias,         // [N]
    const float* __restrict__ residual,     // [M,N] or null
    void* __restrict__ Cout,                // [M,N] fp32 or bf16
    int M, int N, int K, int act, int outBf16)
{
    __shared__ __align__(16) __hip_bfloat16 As[128 * 32];
    __shared__ __align__(16) __hip_bfloat16 Bs[128 * 32];

    const int tid  = threadIdx.x;
    const int wv   = tid >> 6;
    const int lane = tid & 63;
    const int ln15 = lane & 15;
    const int lq   = lane >> 4;
    const int wm   = (wv >> 1) * 64;
    const int wn   = (wv & 1) * 64;
    const int row0 = blockIdx.y * 128;
    const int col0 = blockIdx.x * 128;

    const int sr = wv * 16 + (lane >> 2);
    const int sq = (lane & 3) * 8;

    f32x4 acc[4][4];
#pragma unroll
    for (int i = 0; i < 4; ++i)
#pragma unroll
        for (int j = 0; j < 4; ++j) acc[i][j] = (f32x4){0.f, 0.f, 0.f, 0.f};

    for (int k0 = 0; k0 < K; k0 += 32) {
        __syncthreads();
#pragma unroll
        for (int i = 0; i < 2; ++i) {
            const int r = i * 64 + sr;
            async16(A  + (size_t)(row0 + r) * K + k0 + sq, As + r * 32);
            async16(Bt + (size_t)(col0 + r) * K + k0 + sq, Bs + r * 32);
        }
        __syncthreads();

        bf16x8 af[4], bfr[4];
#pragma unroll
        for (int mi = 0; mi < 4; ++mi)
            af[mi] = *(const bf16x8*)&As[(wm + mi * 16 + ln15) * 32 + lq * 8];
#pragma unroll
        for (int ni = 0; ni < 4; ++ni)
            bfr[ni] = *(const bf16x8*)&Bs[(wn + ni * 16 + ln15) * 32 + lq * 8];
#pragma unroll
        for (int mi = 0; mi < 4; ++mi)
#pragma unroll
            for (int ni = 0; ni < 4; ++ni)
                acc[mi][ni] = __builtin_amdgcn_mfma_f32_16x16x32_bf16(
                    af[mi], bfr[ni], acc[mi][ni], 0, 0, 0);
    }

#pragma unroll
    for (int mi = 0; mi < 4; ++mi) {
#pragma unroll
        for (int ni = 0; ni < 4; ++ni) {
            const int gc = col0 + wn + ni * 16 + ln15;
            const float bv = bias[gc];
#pragma unroll
            for (int r = 0; r < 4; ++r) {
                const int gr = row0 + wm + mi * 16 + lq * 4 + r;
                float v = acc[mi][ni][r] + bv;
                if (act == 1) v = gelu_exact(v);
                if (residual) v += residual[(size_t)gr * N + gc];
                if (outBf16)
                    ((__hip_bfloat16*)Cout)[(size_t)gr * N + gc] = __float2bfloat16(v);
                else
                    ((float*)Cout)[(size_t)gr * N + gc] = v;
            }
        }
    }
}

// ---------------------------------------- qkv GEMM with routing epilogue
// A[4096,1024] bf16 @ Bt[3072,1024] bf16 -> Qb/Kb [b,h,q,d], Vtb [b,h,d,q] bf16
__global__ __launch_bounds__(256) void mfma_qkv_kernel(
    const __hip_bfloat16* __restrict__ A,
    const __hip_bfloat16* __restrict__ Bt,
    const float* __restrict__ bias,
    __hip_bfloat16* __restrict__ Qb,
    __hip_bfloat16* __restrict__ Kb,
    __hip_bfloat16* __restrict__ Vtb)
{
    const int K = D_MODEL, N = C3;
    __shared__ __align__(16) __hip_bfloat16 As[128 * 32];
    __shared__ __align__(16) __hip_bfloat16 Bs[128 * 32];

    const int tid  = threadIdx.x;
    const int wv   = tid >> 6;
    const int lane = tid & 63;
    const int ln15 = lane & 15;
    const int lq   = lane >> 4;
    const int wm   = (wv >> 1) * 64;
    const int wn   = (wv & 1) * 64;
    const int row0 = blockIdx.y * 128;
    const int col0 = blockIdx.x * 128;

    const int sr = wv * 16 + (lane >> 2);
    const int sq = (lane & 3) * 8;

    f32x4 acc[4][4];
#pragma unroll
    for (int i = 0; i < 4; ++i)
#pragma unroll
        for (int j = 0; j < 4; ++j) acc[i][j] = (f32x4){0.f, 0.f, 0.f, 0.f};

    for (int k0 = 0; k0 < K; k0 += 32) {
        __syncthreads();
#pragma unroll
        for (int i = 0; i < 2; ++i) {
            const int r = i * 64 + sr;
            async16(A  + (size_t)(row0 + r) * K + k0 + sq, As + r * 32);
            async16(Bt + (size_t)(col0 + r) * K + k0 + sq, Bs + r * 32);
        }
        __syncthreads();

        bf16x8 af[4], bfr[4];
#pragma unroll
        for (int mi = 0; mi < 4; ++mi)
            af[mi] = *(const bf16x8*)&As[(wm + mi * 16 + ln15) * 32 + lq * 8];
#pragma unroll
        for (int ni = 0; ni < 4; ++ni)
            bfr[ni] = *(const bf16x8*)&Bs[(wn + ni * 16 + ln15) * 32 + lq * 8];
#pragma unroll
        for (int mi = 0; mi < 4; ++mi)
#pragma unroll
            for (int ni = 0; ni < 4; ++ni)
                acc[mi][ni] = __builtin_amdgcn_mfma_f32_16x16x32_bf16(
                    af[mi], bfr[ni], acc[mi][ni], 0, 0, 0);
    }

#pragma unroll
    for (int mi = 0; mi < 4; ++mi) {
        const int gr0 = row0 + wm + mi * 16 + lq * 4;   // + r
        const int bb  = gr0 >> 11;
        const int q0  = gr0 & 2047;
#pragma unroll
        for (int ni = 0; ni < 4; ++ni) {
            const int gc  = col0 + wn + ni * 16 + ln15;
            const float bv = bias[gc];
            const int sec = gc >> 10;            // 0:Q 1:K 2:V
            const int hd  = (gc & 1023) >> 6;
            const int d   = gc & 63;
            if (sec == 2) {
                // Vtb[(bb,hd,d), q0..q0+3] -- contiguous, pack 8B
                unsigned short u[4];
#pragma unroll
                for (int r = 0; r < 4; ++r) {
                    __hip_bfloat16 e = __float2bfloat16(acc[mi][ni][r] + bv);
                    u[r] = *(unsigned short*)&e;
                }
                uint2 pk;
                pk.x = (unsigned int)u[0] | ((unsigned int)u[1] << 16);
                pk.y = (unsigned int)u[2] | ((unsigned int)u[3] << 16);
                *(uint2*)(Vtb + ((size_t)((bb * N_HEAD + hd) * D_HEAD + d)) * SEQ_T + q0) = pk;
            } else {
                __hip_bfloat16* dst = (sec == 0 ? Qb : Kb)
                    + ((size_t)((bb * N_HEAD + hd) * SEQ_T + q0)) * D_HEAD + d;
#pragma unroll
                for (int r = 0; r < 4; ++r)
                    dst[(size_t)r * D_HEAD] = __float2bfloat16(acc[mi][ni][r] + bv);
            }
        }
    }
}

// ------------------------------------------------- MFMA flash attention
// 4 waves, Q-tile 128 (32 rows/wave), K-tile 128, 16x16x32 bf16 MFMA.
#define ATQ 128
#define ATK 128
#define KP  72    // Ks row stride (elems)
#define VP  136   // Vts / Ps row stride (elems)

__global__ __launch_bounds__(256) void mfma_attn_kernel(
    const __hip_bfloat16* __restrict__ Qb,
    const __hip_bfloat16* __restrict__ Kb,
    const __hip_bfloat16* __restrict__ Vtb,
    __hip_bfloat16* __restrict__ y)
{
    __shared__ __align__(16) __hip_bfloat16 Ks[ATK * KP];      // [j][d]
    __shared__ __align__(16) __hip_bfloat16 Vts[D_HEAD * VP];  // [d][j]
    __shared__ __align__(16) __hip_bfloat16 Ps[ATQ * VP];      // [q][j]

    const int qt   = gridDim.x - 1 - blockIdx.x;  // big tiles first
    const int h    = blockIdx.y;
    const int b    = blockIdx.z;
    const int tid  = threadIdx.x;
    const int wv   = tid >> 6;
    const int lane = tid & 63;
    const int ln15 = lane & 15;
    const int lq   = lane >> 4;
    const int qbase = qt * ATQ;
    const int wq0   = wv * 32;

    const __hip_bfloat16* Qh = Qb + (size_t)(b * N_HEAD + h) * SEQ_T * D_HEAD;
    const __hip_bfloat16* Kh = Kb + (size_t)(b * N_HEAD + h) * SEQ_T * D_HEAD;
    const __hip_bfloat16* Vh = Vtb + (size_t)(b * N_HEAD + h) * D_HEAD * SEQ_T;

    // Q fragments in registers: rows wq0 + mi*16 + ln15, k = kc*32 + lq*8
    bf16x8 qf[2][2];
#pragma unroll
    for (int mi = 0; mi < 2; ++mi)
#pragma unroll
        for (int kc = 0; kc < 2; ++kc)
            qf[mi][kc] = *(const bf16x8*)(Qh
                + (size_t)(qbase + wq0 + mi * 16 + ln15) * D_HEAD + kc * 32 + lq * 8);

    f32x4 Oacc[2][4];
    float m_run[2][4], l_run[2][4];
#pragma unroll
    for (int mi = 0; mi < 2; ++mi)
#pragma unroll
        for (int r = 0; r < 4; ++r) {
            m_run[mi][r] = -INFINITY; l_run[mi][r] = 0.f;
        }
#pragma unroll
    for (int mi = 0; mi < 2; ++mi)
#pragma unroll
        for (int di = 0; di < 4; ++di) Oacc[mi][di] = (f32x4){0.f, 0.f, 0.f, 0.f};

    for (int t = 0; t <= qt; ++t) {
        const int kb = t * ATK;
        __syncthreads();   // prev iter done reading Ks/Vts
        // stage K tile [128][64]: 1024 chunks of 8 elems; 8 lanes per row
#pragma unroll
        for (int i = 0; i < 4; ++i) {
            const int ch = tid + i * 256;
            const int r = ch >> 3, c8 = (ch & 7) * 8;
            *(bf16x8*)&Ks[r * KP + c8] = *(const bf16x8*)(Kh + (size_t)(kb + r) * D_HEAD + c8);
        }
        // stage Vt tile [64][128]: 16 lanes per row
#pragma unroll
        for (int i = 0; i < 4; ++i) {
            const int ch = tid + i * 256;
            const int r = ch >> 4, c8 = (ch & 15) * 8;
            *(bf16x8*)&Vts[r * VP + c8] = *(const bf16x8*)(Vh + (size_t)r * SEQ_T + kb + c8);
        }
        __syncthreads();

        // ---- S = Q K^T : rows 32 (2 mi-frags), cols 128 (8 ni-frags)
        f32x4 s[2][8];
#pragma unroll
        for (int mi = 0; mi < 2; ++mi)
#pragma unroll
            for (int ni = 0; ni < 8; ++ni) s[mi][ni] = (f32x4){0.f, 0.f, 0.f, 0.f};
#pragma unroll
        for (int ni = 0; ni < 8; ++ni) {
            const bf16x8 kf0 = *(const bf16x8*)&Ks[(ni * 16 + ln15) * KP + lq * 8];
            const bf16x8 kf1 = *(const bf16x8*)&Ks[(ni * 16 + ln15) * KP + 32 + lq * 8];
#pragma unroll
            for (int mi = 0; mi < 2; ++mi) {
                s[mi][ni] = __builtin_amdgcn_mfma_f32_16x16x32_bf16(qf[mi][0], kf0, s[mi][ni], 0, 0, 0);
                s[mi][ni] = __builtin_amdgcn_mfma_f32_16x16x32_bf16(qf[mi][1], kf1, s[mi][ni], 0, 0, 0);
            }
        }

        // ---- scale + causal mask (diagonal tile only)
        const bool diag = (t == qt);
#pragma unroll
        for (int mi = 0; mi < 2; ++mi)
#pragma unroll
            for (int ni = 0; ni < 8; ++ni)
#pragma unroll
                for (int r = 0; r < 4; ++r) {
                    float v = s[mi][ni][r] * 0.125f;
                    if (diag && (ni * 16 + ln15) > (wq0 + mi * 16 + lq * 4 + r))
                        v = -INFINITY;
                    s[mi][ni][r] = v;
                }

        // ---- online softmax (rows are wave-local; reduce over 16 ln15 lanes)
#pragma unroll
        for (int mi = 0; mi < 2; ++mi)
#pragma unroll
            for (int r = 0; r < 4; ++r) {
                float tmax = s[mi][0][r];
#pragma unroll
                for (int ni = 1; ni < 8; ++ni) tmax = fmaxf(tmax, s[mi][ni][r]);
                tmax = fmaxf(tmax, __shfl_xor(tmax, 1));
                tmax = fmaxf(tmax, __shfl_xor(tmax, 2));
                tmax = fmaxf(tmax, __shfl_xor(tmax, 4));
                tmax = fmaxf(tmax, __shfl_xor(tmax, 8));
                const float mnew = fmaxf(m_run[mi][r], tmax);
                const float alpha = __expf(m_run[mi][r] - mnew);
                float psum = 0.f;
#pragma unroll
                for (int ni = 0; ni < 8; ++ni) {
                    const float p = __expf(s[mi][ni][r] - mnew);
                    s[mi][ni][r] = p;
                    psum += p;
                }
                psum += __shfl_xor(psum, 1);
                psum += __shfl_xor(psum, 2);
                psum += __shfl_xor(psum, 4);
                psum += __shfl_xor(psum, 8);
                l_run[mi][r] = alpha * l_run[mi][r] + psum;
                m_run[mi][r] = mnew;
#pragma unroll
                for (int di = 0; di < 4; ++di) Oacc[mi][di][r] *= alpha;
            }

        // ---- P -> LDS (C-layout write; wave-private rows, no barrier)
#pragma unroll
        for (int mi = 0; mi < 2; ++mi)
#pragma unroll
            for (int ni = 0; ni < 8; ++ni)
#pragma unroll
                for (int r = 0; r < 4; ++r)
                    Ps[(wq0 + mi * 16 + lq * 4 + r) * VP + ni * 16 + ln15] =
                        __float2bfloat16(s[mi][ni][r]);

        // ---- O += P V  (P as A-operand, Vt as B-operand)
        bf16x8 pf[2][4];
#pragma unroll
        for (int mi = 0; mi < 2; ++mi)
#pragma unroll
            for (int jc = 0; jc < 4; ++jc)
                pf[mi][jc] = *(const bf16x8*)&Ps[(wq0 + mi * 16 + ln15) * VP + jc * 32 + lq * 8];
#pragma unroll
        for (int di = 0; di < 4; ++di) {
            bf16x8 vf[4];
#pragma unroll
            for (int jc = 0; jc < 4; ++jc)
                vf[jc] = *(const bf16x8*)&Vts[(di * 16 + ln15) * VP + jc * 32 + lq * 8];
#pragma unroll
            for (int mi = 0; mi < 2; ++mi)
#pragma unroll
                for (int jc = 0; jc < 4; ++jc)
                    Oacc[mi][di] = __builtin_amdgcn_mfma_f32_16x16x32_bf16(
                        pf[mi][jc], vf[jc], Oacc[mi][di], 0, 0, 0);
        }
    }

    // ---- epilogue: y[b, q, h*64+d] = O / l
#pragma unroll
    for (int mi = 0; mi < 2; ++mi)
#pragma unroll
        for (int di = 0; di < 4; ++di)
#pragma unroll
            for (int r = 0; r < 4; ++r) {
                const int gq = qbase + wq0 + mi * 16 + lq * 4 + r;
                const int d  = di * 16 + ln15;
                y[((size_t)b * SEQ_T + gq) * D_MODEL + h * D_HEAD + d] =
                    __float2bfloat16(Oacc[mi][di][r] / l_run[mi][r]);
            }
}

// ------------------------------------------------------------------ launch
extern "C" void kernel_launch(void* const* d_in, const int* in_sizes, int n_in,
                              void* d_out, int out_size, void* d_ws, size_t ws_size,
                              hipStream_t stream)
{
    const float* x      = (const float*)d_in[0];
    const float* ln1_w  = (const float*)d_in[1];
    const float* ln1_b  = (const float*)d_in[2];
    const float* attn_w = (const float*)d_in[3];
    const float* attn_b = (const float*)d_in[4];
    const float* proj_w = (const float*)d_in[5];
    const float* proj_b = (const float*)d_in[6];
    const float* ln2_w  = (const float*)d_in[7];
    const float* ln2_b  = (const float*)d_in[8];
    const float* fc_w   = (const float*)d_in[9];
    const float* fc_b   = (const float*)d_in[10];
    const float* fc2_w  = (const float*)d_in[11];
    const float* fc2_b  = (const float*)d_in[12];
    float* out = (float*)d_out;

    // ws layout (bytes). Qb/Kb/Vtb (steps 2-3) overlap h_bf (steps 6-7).
    //   Qb   @ 0   : 8MB bf16 [b,h,q,d]
    //   Kb   @ 8M  : 8MB bf16 [b,h,q,d]
    //   Vtb  @ 16M : 8MB bf16 [b,h,d,q]
    //   h_bf @ 0   : 32MB bf16 (overlaps the above; disjoint lifetime)
    //   ln_buf @ 32M : 8MB bf16
    //   y_buf  @ 40M : 8MB bf16
    //   xmid   @ 48M : 16MB fp32
    //   attn_wt @ 64M : 6MB ; proj_wt @ 70M : 2MB ; fc_wt @ 72M : 8MB ; fc2_wt @ 80M : 8MB
    char* ws = (char*)d_ws;
    __hip_bfloat16* Qb      = (__hip_bfloat16*)(ws);
    __hip_bfloat16* Kb      = (__hip_bfloat16*)(ws + (size_t)8  * 1024 * 1024);
    __hip_bfloat16* Vtb     = (__hip_bfloat16*)(ws + (size_t)16 * 1024 * 1024);
    __hip_bfloat16* h_bf    = (__hip_bfloat16*)(ws);
    __hip_bfloat16* ln_buf  = (__hip_bfloat16*)(ws + (size_t)32 * 1024 * 1024);
    __hip_bfloat16* y_buf   = (__hip_bfloat16*)(ws + (size_t)40 * 1024 * 1024);
    float*          xmid    = (float*)(ws + (size_t)48 * 1024 * 1024);
    __hip_bfloat16* attn_wt = (__hip_bfloat16*)(ws + (size_t)64 * 1024 * 1024);
    __hip_bfloat16* proj_wt = (__hip_bfloat16*)(ws + (size_t)70 * 1024 * 1024);
    __hip_bfloat16* fc_wt   = (__hip_bfloat16*)(ws + (size_t)72 * 1024 * 1024);
    __hip_bfloat16* fc2_wt  = (__hip_bfloat16*)(ws + (size_t)80 * 1024 * 1024);

    dim3 blk256(256);

    // 0. weight transposes (fp32 [K,N] -> bf16 [N,K])
    transpose_bf16_kernel<<<dim3(C3 / 32, D_MODEL / 32), blk256, 0, stream>>>(
        attn_w, attn_wt, D_MODEL, C3);
    transpose_bf16_kernel<<<dim3(D_MODEL / 32, D_MODEL / 32), blk256, 0, stream>>>(
        proj_w, proj_wt, D_MODEL, D_MODEL);
    transpose_bf16_kernel<<<dim3(D_FF / 32, D_MODEL / 32), blk256, 0, stream>>>(
        fc_w, fc_wt, D_MODEL, D_FF);
    transpose_bf16_kernel<<<dim3(D_MODEL / 32, D_FF / 32), blk256, 0, stream>>>(
        fc2_w, fc2_wt, D_FF, D_MODEL);

    // 1. ln1(x) -> ln_buf (bf16)
    ln_kernel<<<dim3(NROWS), blk256, 0, stream>>>(x, ln1_w, ln1_b, ln_buf, D_MODEL);

    // 2. qkv GEMM -> Qb/Kb/Vtb (bf16, per-head layouts)
    mfma_qkv_kernel<<<dim3(C3 / 128, NROWS / 128), blk256, 0, stream>>>(
        ln_buf, attn_wt, attn_b, Qb, Kb, Vtb);

    // 3. MFMA flash attention -> y_buf (bf16)
    mfma_attn_kernel<<<dim3(SEQ_T / ATQ, N_HEAD, BATCH), blk256, 0, stream>>>(
        Qb, Kb, Vtb, y_buf);

    // 4. xmid = x + y_buf @ proj_w + proj_b  (fp32)
    mfma_gemm_kernel<<<dim3(D_MODEL / 128, NROWS / 128), blk256, 0, stream>>>(
        y_buf, proj_wt, proj_b, x, xmid, NROWS, D_MODEL, D_MODEL, 0, 0);

    // 5. ln2(xmid) -> ln_buf (bf16)
    ln_kernel<<<dim3(NROWS), blk256, 0, stream>>>(xmid, ln2_w, ln2_b, ln_buf, D_MODEL);

    // 6. h = gelu(ln_buf @ fc_w + fc_b) -> bf16
    mfma_gemm_kernel<<<dim3(D_FF / 128, NROWS / 128), blk256, 0, stream>>>(
        ln_buf, fc_wt, fc_b, nullptr, h_bf, NROWS, D_FF, D_MODEL, 1, 1);

    // 7. out = xmid + h @ fc2_w + fc2_b  (fp32)
    mfma_gemm_kernel<<<dim3(D_MODEL / 128, NROWS / 128), blk256, 0, stream>>>(
        h_bf, fc2_wt, fc2_b, xmid, out, NROWS, D_MODEL, D_FF, 0, 0);
}

// Round 5
// 476.852 us; speedup vs baseline: 9.1764x; 1.0821x over previous
//
#include <hip/hip_runtime.h>
#include <hip/hip_bf16.h>
#include <math.h>

// Transformer block. Round 5: balanced S^T-form MFMA flash attention.
// D_MODEL=1024, N_HEAD=16, D_HEAD=64, EXP=4, B=2, T=2048, EPS=1e-5

#define D_MODEL 1024
#define N_HEAD  16
#define D_HEAD  64
#define SEQ_T   2048
#define BATCH   2
#define NROWS   (BATCH * SEQ_T)   // 4096
#define C3      (3 * D_MODEL)     // 3072
#define D_FF    (4 * D_MODEL)     // 4096

typedef __bf16 bf16x8 __attribute__((ext_vector_type(8)));
typedef float  f32x4  __attribute__((ext_vector_type(4)));

// ---------------------------------------------------------------- LayerNorm
__global__ __launch_bounds__(256) void ln_kernel(
    const float* __restrict__ in, const float* __restrict__ w,
    const float* __restrict__ b, __hip_bfloat16* __restrict__ out, int D)
{
    const int row = blockIdx.x;
    const int tid = threadIdx.x;
    const float* x = in + (size_t)row * D;

    float s = 0.f, s2 = 0.f;
    for (int i = tid; i < D; i += 256) {
        float v = x[i];
        s += v; s2 += v * v;
    }
    __shared__ float rs[256], rs2[256];
    rs[tid] = s; rs2[tid] = s2;
    __syncthreads();
    for (int off = 128; off > 0; off >>= 1) {
        if (tid < off) { rs[tid] += rs[tid + off]; rs2[tid] += rs2[tid + off]; }
        __syncthreads();
    }
    const float mu   = rs[0] / D;
    const float var  = rs2[0] / D - mu * mu;
    const float rstd = rsqrtf(var + 1e-5f);

    __hip_bfloat16* o = out + (size_t)row * D;
    for (int i = tid; i < D; i += 256)
        o[i] = __float2bfloat16((x[i] - mu) * rstd * w[i] + b[i]);
}

// ------------------------------------------- weight transpose + bf16 cast
__global__ __launch_bounds__(256) void transpose_bf16_kernel(
    const float* __restrict__ W, __hip_bfloat16* __restrict__ Wt, int K, int N)
{
    __shared__ float t[32][33];
    const int tx = threadIdx.x & 31;
    const int ty = threadIdx.x >> 5;
    const int k0 = blockIdx.y * 32;
    const int n0 = blockIdx.x * 32;
#pragma unroll
    for (int i = 0; i < 4; ++i)
        t[ty + 8 * i][tx] = W[(size_t)(k0 + ty + 8 * i) * N + n0 + tx];
    __syncthreads();
#pragma unroll
    for (int i = 0; i < 4; ++i)
        Wt[(size_t)(n0 + ty + 8 * i) * K + k0 + tx] =
            __float2bfloat16(t[tx][ty + 8 * i]);
}

// ----------------------------------------------------------- bf16 MFMA GEMM
__device__ __forceinline__ void async16(const __hip_bfloat16* g, __hip_bfloat16* l)
{
    __builtin_amdgcn_global_load_lds(
        (const __attribute__((address_space(1))) void*)g,
        (__attribute__((address_space(3))) void*)l, 16, 0, 0);
}

__device__ __forceinline__ float gelu_exact(float v)
{
    return 0.5f * v * (1.0f + erff(v * 0.70710678118654752f));
}

__global__ __launch_bounds__(256) void mfma_gemm_kernel(
    const __hip_bfloat16* __restrict__ A,   // [M,K]
    const __hip_bfloat16* __restrict__ Bt,  // [N,K]
    const float* __restrict__ bias,         // [N]
    const float* __restrict__ residual,     // [M,N] or null
    void* __restrict__ Cout,                // [M,N] fp32 or bf16
    int M, int N, int K, int act, int outBf16)
{
    __shared__ __align__(16) __hip_bfloat16 As[128 * 32];
    __shared__ __align__(16) __hip_bfloat16 Bs[128 * 32];

    const int tid  = threadIdx.x;
    const int wv   = tid >> 6;
    const int lane = tid & 63;
    const int ln15 = lane & 15;
    const int lq   = lane >> 4;
    const int wm   = (wv >> 1) * 64;
    const int wn   = (wv & 1) * 64;
    const int row0 = blockIdx.y * 128;
    const int col0 = blockIdx.x * 128;

    const int sr = wv * 16 + (lane >> 2);
    const int sq = (lane & 3) * 8;

    f32x4 acc[4][4];
#pragma unroll
    for (int i = 0; i < 4; ++i)
#pragma unroll
        for (int j = 0; j < 4; ++j) acc[i][j] = (f32x4){0.f, 0.f, 0.f, 0.f};

    for (int k0 = 0; k0 < K; k0 += 32) {
        __syncthreads();
#pragma unroll
        for (int i = 0; i < 2; ++i) {
            const int r = i * 64 + sr;
            async16(A  + (size_t)(row0 + r) * K + k0 + sq, As + r * 32);
            async16(Bt + (size_t)(col0 + r) * K + k0 + sq, Bs + r * 32);
        }
        __syncthreads();

        bf16x8 af[4], bfr[4];
#pragma unroll
        for (int mi = 0; mi < 4; ++mi)
            af[mi] = *(const bf16x8*)&As[(wm + mi * 16 + ln15) * 32 + lq * 8];
#pragma unroll
        for (int ni = 0; ni < 4; ++ni)
            bfr[ni] = *(const bf16x8*)&Bs[(wn + ni * 16 + ln15) * 32 + lq * 8];
#pragma unroll
        for (int mi = 0; mi < 4; ++mi)
#pragma unroll
            for (int ni = 0; ni < 4; ++ni)
                acc[mi][ni] = __builtin_amdgcn_mfma_f32_16x16x32_bf16(
                    af[mi], bfr[ni], acc[mi][ni], 0, 0, 0);
    }

#pragma unroll
    for (int mi = 0; mi < 4; ++mi) {
#pragma unroll
        for (int ni = 0; ni < 4; ++ni) {
            const int gc = col0 + wn + ni * 16 + ln15;
            const float bv = bias[gc];
#pragma unroll
            for (int r = 0; r < 4; ++r) {
                const int gr = row0 + wm + mi * 16 + lq * 4 + r;
                float v = acc[mi][ni][r] + bv;
                if (act == 1) v = gelu_exact(v);
                if (residual) v += residual[(size_t)gr * N + gc];
                if (outBf16)
                    ((__hip_bfloat16*)Cout)[(size_t)gr * N + gc] = __float2bfloat16(v);
                else
                    ((float*)Cout)[(size_t)gr * N + gc] = v;
            }
        }
    }
}

// ---------------------------------------- qkv GEMM with routing epilogue
__global__ __launch_bounds__(256) void mfma_qkv_kernel(
    const __hip_bfloat16* __restrict__ A,
    const __hip_bfloat16* __restrict__ Bt,
    const float* __restrict__ bias,
    __hip_bfloat16* __restrict__ Qb,
    __hip_bfloat16* __restrict__ Kb,
    __hip_bfloat16* __restrict__ Vtb)
{
    const int K = D_MODEL, N = C3;
    __shared__ __align__(16) __hip_bfloat16 As[128 * 32];
    __shared__ __align__(16) __hip_bfloat16 Bs[128 * 32];

    const int tid  = threadIdx.x;
    const int wv   = tid >> 6;
    const int lane = tid & 63;
    const int ln15 = lane & 15;
    const int lq   = lane >> 4;
    const int wm   = (wv >> 1) * 64;
    const int wn   = (wv & 1) * 64;
    const int row0 = blockIdx.y * 128;
    const int col0 = blockIdx.x * 128;

    const int sr = wv * 16 + (lane >> 2);
    const int sq = (lane & 3) * 8;

    f32x4 acc[4][4];
#pragma unroll
    for (int i = 0; i < 4; ++i)
#pragma unroll
        for (int j = 0; j < 4; ++j) acc[i][j] = (f32x4){0.f, 0.f, 0.f, 0.f};

    for (int k0 = 0; k0 < K; k0 += 32) {
        __syncthreads();
#pragma unroll
        for (int i = 0; i < 2; ++i) {
            const int r = i * 64 + sr;
            async16(A  + (size_t)(row0 + r) * K + k0 + sq, As + r * 32);
            async16(Bt + (size_t)(col0 + r) * K + k0 + sq, Bs + r * 32);
        }
        __syncthreads();

        bf16x8 af[4], bfr[4];
#pragma unroll
        for (int mi = 0; mi < 4; ++mi)
            af[mi] = *(const bf16x8*)&As[(wm + mi * 16 + ln15) * 32 + lq * 8];
#pragma unroll
        for (int ni = 0; ni < 4; ++ni)
            bfr[ni] = *(const bf16x8*)&Bs[(wn + ni * 16 + ln15) * 32 + lq * 8];
#pragma unroll
        for (int mi = 0; mi < 4; ++mi)
#pragma unroll
            for (int ni = 0; ni < 4; ++ni)
                acc[mi][ni] = __builtin_amdgcn_mfma_f32_16x16x32_bf16(
                    af[mi], bfr[ni], acc[mi][ni], 0, 0, 0);
    }

#pragma unroll
    for (int mi = 0; mi < 4; ++mi) {
        const int gr0 = row0 + wm + mi * 16 + lq * 4;   // + r
        const int bb  = gr0 >> 11;
        const int q0  = gr0 & 2047;
#pragma unroll
        for (int ni = 0; ni < 4; ++ni) {
            const int gc  = col0 + wn + ni * 16 + ln15;
            const float bv = bias[gc];
            const int sec = gc >> 10;            // 0:Q 1:K 2:V
            const int hd  = (gc & 1023) >> 6;
            const int d   = gc & 63;
            if (sec == 2) {
                unsigned short u[4];
#pragma unroll
                for (int r = 0; r < 4; ++r) {
                    __hip_bfloat16 e = __float2bfloat16(acc[mi][ni][r] + bv);
                    u[r] = *(unsigned short*)&e;
                }
                uint2 pk;
                pk.x = (unsigned int)u[0] | ((unsigned int)u[1] << 16);
                pk.y = (unsigned int)u[2] | ((unsigned int)u[3] << 16);
                *(uint2*)(Vtb + ((size_t)((bb * N_HEAD + hd) * D_HEAD + d)) * SEQ_T + q0) = pk;
            } else {
                __hip_bfloat16* dst = (sec == 0 ? Qb : Kb)
                    + ((size_t)((bb * N_HEAD + hd) * SEQ_T + q0)) * D_HEAD + d;
#pragma unroll
                for (int r = 0; r < 4; ++r)
                    dst[(size_t)r * D_HEAD] = __float2bfloat16(acc[mi][ni][r] + bv);
            }
        }
    }
}

// ------------------------------------------------- MFMA flash attention v2
// ATQ=64 q rows/tile, ATK=128 k cols/tile. 4 waves; each wave owns 16 q rows.
// Block p handles the pair of q-tiles (p, 31-p): every block = 17 K-iters.
// S computed TRANSPOSED (A=K, B=Q) so each lane's column is one q row:
// softmax reduce = 2 shfl rounds; P store = packed 8B writes.
#define ATQ 64
#define ATK 128
#define NQT (SEQ_T / ATQ)   // 32
#define KP  72              // Ks row stride (elems, 16B-mult)
#define VP  136             // Vts / Ps row stride (elems, 16B-mult)

__global__ __launch_bounds__(256) void mfma_attn_kernel(
    const __hip_bfloat16* __restrict__ Qb,
    const __hip_bfloat16* __restrict__ Kb,
    const __hip_bfloat16* __restrict__ Vtb,
    __hip_bfloat16* __restrict__ y)
{
    __shared__ __align__(16) __hip_bfloat16 Ks[ATK * KP];      // [j][d]
    __shared__ __align__(16) __hip_bfloat16 Vts[D_HEAD * VP];  // [d][j]
    __shared__ __align__(16) __hip_bfloat16 Ps[ATQ * VP];      // [q][j] / O epilogue

    const int pair = blockIdx.x;   // 0..15
    const int h    = blockIdx.y;
    const int b    = blockIdx.z;
    const int tid  = threadIdx.x;
    const int wv   = tid >> 6;
    const int lane = tid & 63;
    const int ln15 = lane & 15;
    const int lq   = lane >> 4;

    const __hip_bfloat16* Qh = Qb  + (size_t)(b * N_HEAD + h) * SEQ_T * D_HEAD;
    const __hip_bfloat16* Kh = Kb  + (size_t)(b * N_HEAD + h) * SEQ_T * D_HEAD;
    const __hip_bfloat16* Vh = Vtb + (size_t)(b * N_HEAD + h) * D_HEAD * SEQ_T;
    const size_t bT = (size_t)b * SEQ_T;

#pragma unroll 1
    for (int half = 0; half < 2; ++half) {
        const int qt    = half == 0 ? pair : (NQT - 1 - pair);
        const int qbase = qt * ATQ;
        const int ntk   = (qt >> 1) + 1;          // 128-wide K tiles needed
        const int qg    = qbase + wv * 16 + ln15; // this lane's q row (stats owner)

        // Q fragments (16 rows per wave) in registers
        bf16x8 qf[2];
#pragma unroll
        for (int kc = 0; kc < 2; ++kc)
            qf[kc] = *(const bf16x8*)(Qh + (size_t)(qbase + wv * 16 + ln15) * D_HEAD
                                      + kc * 32 + lq * 8);

        f32x4 Oacc[4];
#pragma unroll
        for (int dn = 0; dn < 4; ++dn) Oacc[dn] = (f32x4){0.f, 0.f, 0.f, 0.f};
        float m_run = -INFINITY, l_run = 0.f;     // stats for q = qg

        for (int t = 0; t < ntk; ++t) {
            const int kb = t * ATK;
            __syncthreads();   // prev iter's LDS reads done
            // stage K tile [128][64]
#pragma unroll
            for (int i = 0; i < 4; ++i) {
                const int ch = tid + i * 256;
                const int r = ch >> 3, c8 = (ch & 7) * 8;
                *(bf16x8*)&Ks[r * KP + c8] =
                    *(const bf16x8*)(Kh + (size_t)(kb + r) * D_HEAD + c8);
            }
            // stage Vt tile [64][128]
#pragma unroll
            for (int i = 0; i < 4; ++i) {
                const int ch = tid + i * 256;
                const int r = ch >> 4, c8 = (ch & 15) * 8;
                *(bf16x8*)&Vts[r * VP + c8] =
                    *(const bf16x8*)(Vh + (size_t)r * SEQ_T + kb + c8);
            }
            __syncthreads();

            // ---- S^T[j=128][q=16] : A=K (rows j), B=Q (rows q)
            f32x4 st[8];
#pragma unroll
            for (int jf = 0; jf < 8; ++jf) st[jf] = (f32x4){0.f, 0.f, 0.f, 0.f};
#pragma unroll
            for (int jf = 0; jf < 8; ++jf) {
                const bf16x8 kf0 = *(const bf16x8*)&Ks[(jf * 16 + ln15) * KP + lq * 8];
                const bf16x8 kf1 = *(const bf16x8*)&Ks[(jf * 16 + ln15) * KP + 32 + lq * 8];
                st[jf] = __builtin_amdgcn_mfma_f32_16x16x32_bf16(kf0, qf[0], st[jf], 0, 0, 0);
                st[jf] = __builtin_amdgcn_mfma_f32_16x16x32_bf16(kf1, qf[1], st[jf], 0, 0, 0);
            }

            // ---- scale + causal mask (only the last tile can touch diagonal)
            const bool last = (t == ntk - 1);
#pragma unroll
            for (int jf = 0; jf < 8; ++jf)
#pragma unroll
                for (int r = 0; r < 4; ++r) {
                    float v = st[jf][r] * 0.125f;
                    if (last && (kb + jf * 16 + lq * 4 + r) > qg) v = -INFINITY;
                    st[jf][r] = v;
                }

            // ---- online softmax for q=qg (reduce 32 regs + lanes lq 0..3)
            float tmax = st[0][0];
#pragma unroll
            for (int jf = 0; jf < 8; ++jf)
#pragma unroll
                for (int r = 0; r < 4; ++r) tmax = fmaxf(tmax, st[jf][r]);
            tmax = fmaxf(tmax, __shfl_xor(tmax, 16));
            tmax = fmaxf(tmax, __shfl_xor(tmax, 32));
            const float mnew  = fmaxf(m_run, tmax);
            const float alpha = __expf(m_run - mnew);
            float psum = 0.f;
#pragma unroll
            for (int jf = 0; jf < 8; ++jf)
#pragma unroll
                for (int r = 0; r < 4; ++r) {
                    const float p = __expf(st[jf][r] - mnew);
                    st[jf][r] = p;
                    psum += p;
                }
            psum += __shfl_xor(psum, 16);
            psum += __shfl_xor(psum, 32);
            l_run = alpha * l_run + psum;
            m_run = mnew;

            // redistribute alpha to Oacc layout (row q' = lq*4+r)
            float a4[4];
#pragma unroll
            for (int r = 0; r < 4; ++r) a4[r] = __shfl(alpha, lq * 4 + r);
#pragma unroll
            for (int dn = 0; dn < 4; ++dn)
#pragma unroll
                for (int r = 0; r < 4; ++r) Oacc[dn][r] *= a4[r];

            // ---- P -> LDS, packed 8B (4 consecutive j per lane)
#pragma unroll
            for (int jf = 0; jf < 8; ++jf) {
                __hip_bfloat162 p01 = __float22bfloat162_rn(make_float2(st[jf][0], st[jf][1]));
                __hip_bfloat162 p23 = __float22bfloat162_rn(make_float2(st[jf][2], st[jf][3]));
                uint2 pk;
                pk.x = *(unsigned int*)&p01;
                pk.y = *(unsigned int*)&p23;
                *(uint2*)&Ps[(wv * 16 + ln15) * VP + jf * 16 + lq * 4] = pk;
            }

            // ---- O += P V   (A=P rows q, B=Vt rows d) — wave-private Ps rows
            bf16x8 pf[4];
#pragma unroll
            for (int jc = 0; jc < 4; ++jc)
                pf[jc] = *(const bf16x8*)&Ps[(wv * 16 + ln15) * VP + jc * 32 + lq * 8];
#pragma unroll
            for (int dn = 0; dn < 4; ++dn) {
#pragma unroll
                for (int jc = 0; jc < 4; ++jc) {
                    const bf16x8 vf = *(const bf16x8*)&Vts[(dn * 16 + ln15) * VP + jc * 32 + lq * 8];
                    Oacc[dn] = __builtin_amdgcn_mfma_f32_16x16x32_bf16(
                        pf[jc], vf, Oacc[dn], 0, 0, 0);
                }
            }
        }

        // ---- epilogue: O row q' = wv*16 + lq*4 + r, col d = dn*16 + ln15
        float il[4];
#pragma unroll
        for (int r = 0; r < 4; ++r) il[r] = 1.0f / __shfl(l_run, lq * 4 + r);
        // transpose through Ps (wave-private rows), then coalesced 16B stores
#pragma unroll
        for (int dn = 0; dn < 4; ++dn)
#pragma unroll
            for (int r = 0; r < 4; ++r)
                Ps[(wv * 16 + lq * 4 + r) * VP + dn * 16 + ln15] =
                    __float2bfloat16(Oacc[dn][r] * il[r]);
        const int r2 = lane >> 3, c8 = (lane & 7) * 8;
#pragma unroll
        for (int i = 0; i < 2; ++i) {
            const int row = wv * 16 + r2 + 8 * i;
            const bf16x8 val = *(const bf16x8*)&Ps[row * VP + c8];
            *(bf16x8*)(y + (bT + qbase + row) * D_MODEL + h * D_HEAD + c8) = val;
        }
    }
}

// ------------------------------------------------------------------ launch
extern "C" void kernel_launch(void* const* d_in, const int* in_sizes, int n_in,
                              void* d_out, int out_size, void* d_ws, size_t ws_size,
                              hipStream_t stream)
{
    const float* x      = (const float*)d_in[0];
    const float* ln1_w  = (const float*)d_in[1];
    const float* ln1_b  = (const float*)d_in[2];
    const float* attn_w = (const float*)d_in[3];
    const float* attn_b = (const float*)d_in[4];
    const float* proj_w = (const float*)d_in[5];
    const float* proj_b = (const float*)d_in[6];
    const float* ln2_w  = (const float*)d_in[7];
    const float* ln2_b  = (const float*)d_in[8];
    const float* fc_w   = (const float*)d_in[9];
    const float* fc_b   = (const float*)d_in[10];
    const float* fc2_w  = (const float*)d_in[11];
    const float* fc2_b  = (const float*)d_in[12];
    float* out = (float*)d_out;

    char* ws = (char*)d_ws;
    __hip_bfloat16* Qb      = (__hip_bfloat16*)(ws);
    __hip_bfloat16* Kb      = (__hip_bfloat16*)(ws + (size_t)8  * 1024 * 1024);
    __hip_bfloat16* Vtb     = (__hip_bfloat16*)(ws + (size_t)16 * 1024 * 1024);
    __hip_bfloat16* h_bf    = (__hip_bfloat16*)(ws);
    __hip_bfloat16* ln_buf  = (__hip_bfloat16*)(ws + (size_t)32 * 1024 * 1024);
    __hip_bfloat16* y_buf   = (__hip_bfloat16*)(ws + (size_t)40 * 1024 * 1024);
    float*          xmid    = (float*)(ws + (size_t)48 * 1024 * 1024);
    __hip_bfloat16* attn_wt = (__hip_bfloat16*)(ws + (size_t)64 * 1024 * 1024);
    __hip_bfloat16* proj_wt = (__hip_bfloat16*)(ws + (size_t)70 * 1024 * 1024);
    __hip_bfloat16* fc_wt   = (__hip_bfloat16*)(ws + (size_t)72 * 1024 * 1024);
    __hip_bfloat16* fc2_wt  = (__hip_bfloat16*)(ws + (size_t)80 * 1024 * 1024);

    dim3 blk256(256);

    // 0. weight transposes (fp32 [K,N] -> bf16 [N,K])
    transpose_bf16_kernel<<<dim3(C3 / 32, D_MODEL / 32), blk256, 0, stream>>>(
        attn_w, attn_wt, D_MODEL, C3);
    transpose_bf16_kernel<<<dim3(D_MODEL / 32, D_MODEL / 32), blk256, 0, stream>>>(
        proj_w, proj_wt, D_MODEL, D_MODEL);
    transpose_bf16_kernel<<<dim3(D_FF / 32, D_MODEL / 32), blk256, 0, stream>>>(
        fc_w, fc_wt, D_MODEL, D_FF);
    transpose_bf16_kernel<<<dim3(D_MODEL / 32, D_FF / 32), blk256, 0, stream>>>(
        fc2_w, fc2_wt, D_FF, D_MODEL);

    // 1. ln1(x) -> ln_buf (bf16)
    ln_kernel<<<dim3(NROWS), blk256, 0, stream>>>(x, ln1_w, ln1_b, ln_buf, D_MODEL);

    // 2. qkv GEMM -> Qb/Kb/Vtb (bf16, per-head layouts)
    mfma_qkv_kernel<<<dim3(C3 / 128, NROWS / 128), blk256, 0, stream>>>(
        ln_buf, attn_wt, attn_b, Qb, Kb, Vtb);

    // 3. MFMA flash attention -> y_buf (bf16); 16 balanced pairs of q-tiles
    mfma_attn_kernel<<<dim3(NQT / 2, N_HEAD, BATCH), blk256, 0, stream>>>(
        Qb, Kb, Vtb, y_buf);

    // 4. xmid = x + y_buf @ proj_w + proj_b  (fp32)
    mfma_gemm_kernel<<<dim3(D_MODEL / 128, NROWS / 128), blk256, 0, stream>>>(
        y_buf, proj_wt, proj_b, x, xmid, NROWS, D_MODEL, D_MODEL, 0, 0);

    // 5. ln2(xmid) -> ln_buf (bf16)
    ln_kernel<<<dim3(NROWS), blk256, 0, stream>>>(xmid, ln2_w, ln2_b, ln_buf, D_MODEL);

    // 6. h = gelu(ln_buf @ fc_w + fc_b) -> bf16
    mfma_gemm_kernel<<<dim3(D_FF / 128, NROWS / 128), blk256, 0, stream>>>(
        ln_buf, fc_wt, fc_b, nullptr, h_bf, NROWS, D_FF, D_MODEL, 1, 1);

    // 7. out = xmid + h @ fc2_w + fc2_b  (fp32)
    mfma_gemm_kernel<<<dim3(D_MODEL / 128, NROWS / 128), blk256, 0, stream>>>(
        h_bf, fc2_wt, fc2_b, xmid, out, NROWS, D_MODEL, D_FF, 0, 0);
}

// Round 6
// 457.752 us; speedup vs baseline: 9.5592x; 1.0417x over previous
//
#include <hip/hip_runtime.h>
#include <hip/hip_bf16.h>
#include <math.h>

// Transformer block. Round 6: double-buffered MFMA GEMMs + L2 swizzle +
// merged weight-transpose launch. Attention unchanged from Round 5.
// D_MODEL=1024, N_HEAD=16, D_HEAD=64, EXP=4, B=2, T=2048, EPS=1e-5

#define D_MODEL 1024
#define N_HEAD  16
#define D_HEAD  64
#define SEQ_T   2048
#define BATCH   2
#define NROWS   (BATCH * SEQ_T)   // 4096
#define C3      (3 * D_MODEL)     // 3072
#define D_FF    (4 * D_MODEL)     // 4096

typedef __bf16 bf16x8 __attribute__((ext_vector_type(8)));
typedef float  f32x4  __attribute__((ext_vector_type(4)));

// ---------------------------------------------------------------- LayerNorm
__global__ __launch_bounds__(256) void ln_kernel(
    const float* __restrict__ in, const float* __restrict__ w,
    const float* __restrict__ b, __hip_bfloat16* __restrict__ out, int D)
{
    const int row = blockIdx.x;
    const int tid = threadIdx.x;
    const float* x = in + (size_t)row * D;

    float s = 0.f, s2 = 0.f;
    for (int i = tid; i < D; i += 256) {
        float v = x[i];
        s += v; s2 += v * v;
    }
    __shared__ float rs[256], rs2[256];
    rs[tid] = s; rs2[tid] = s2;
    __syncthreads();
    for (int off = 128; off > 0; off >>= 1) {
        if (tid < off) { rs[tid] += rs[tid + off]; rs2[tid] += rs2[tid + off]; }
        __syncthreads();
    }
    const float mu   = rs[0] / D;
    const float var  = rs2[0] / D - mu * mu;
    const float rstd = rsqrtf(var + 1e-5f);

    __hip_bfloat16* o = out + (size_t)row * D;
    for (int i = tid; i < D; i += 256)
        o[i] = __float2bfloat16((x[i] - mu) * rstd * w[i] + b[i]);
}

// -------------------------------- merged weight transpose + bf16 cast (x4)
// tiles: attn 32x96=3072 | proj 32x32=1024 | fc 32x128=4096 | fc2 128x32=4096
__global__ __launch_bounds__(256) void transpose_all_kernel(
    const float* __restrict__ attn_w, const float* __restrict__ proj_w,
    const float* __restrict__ fc_w,   const float* __restrict__ fc2_w,
    __hip_bfloat16* __restrict__ attn_wt, __hip_bfloat16* __restrict__ proj_wt,
    __hip_bfloat16* __restrict__ fc_wt,   __hip_bfloat16* __restrict__ fc2_wt)
{
    __shared__ float t[32][33];
    int tb = blockIdx.x;
    const float* W; __hip_bfloat16* Wt; int K, N;
    if (tb < 3072)      { W = attn_w; Wt = attn_wt; K = D_MODEL; N = C3; }
    else if (tb < 4096) { tb -= 3072; W = proj_w; Wt = proj_wt; K = D_MODEL; N = D_MODEL; }
    else if (tb < 8192) { tb -= 4096; W = fc_w;   Wt = fc_wt;   K = D_MODEL; N = D_FF; }
    else                { tb -= 8192; W = fc2_w;  Wt = fc2_wt;  K = D_FF;    N = D_MODEL; }
    const int ntx = N >> 5;
    const int k0 = (tb / ntx) * 32;
    const int n0 = (tb % ntx) * 32;

    const int tx = threadIdx.x & 31;
    const int ty = threadIdx.x >> 5;
#pragma unroll
    for (int i = 0; i < 4; ++i)
        t[ty + 8 * i][tx] = W[(size_t)(k0 + ty + 8 * i) * N + n0 + tx];
    __syncthreads();
#pragma unroll
    for (int i = 0; i < 4; ++i)
        Wt[(size_t)(n0 + ty + 8 * i) * K + k0 + tx] =
            __float2bfloat16(t[tx][ty + 8 * i]);
}

// ----------------------------------------------------------- bf16 MFMA GEMM
__device__ __forceinline__ void async16(const __hip_bfloat16* g, __hip_bfloat16* l)
{
    __builtin_amdgcn_global_load_lds(
        (const __attribute__((address_space(1))) void*)g,
        (__attribute__((address_space(3))) void*)l, 16, 0, 0);
}

__device__ __forceinline__ float gelu_exact(float v)
{
    return 0.5f * v * (1.0f + erff(v * 0.70710678118654752f));
}

// L2 swizzle: walk 4 row-tiles before advancing a column (nby % 4 == 0 here).
__device__ __forceinline__ void swizzle_bxy(int& bx, int& by)
{
    const int nbx = gridDim.x;
    const int lin = blockIdx.y * nbx + blockIdx.x;
    const int stripe = 4 * nbx;
    const int s = lin / stripe;
    const int rem = lin - s * stripe;
    by = s * 4 + (rem & 3);
    bx = rem >> 2;
}

__global__ __launch_bounds__(256) void mfma_gemm_kernel(
    const __hip_bfloat16* __restrict__ A,   // [M,K]
    const __hip_bfloat16* __restrict__ Bt,  // [N,K]
    const float* __restrict__ bias,         // [N]
    const float* __restrict__ residual,     // [M,N] or null
    void* __restrict__ Cout,                // [M,N] fp32 or bf16
    int M, int N, int K, int act, int outBf16)
{
    __shared__ __align__(16) __hip_bfloat16 As[2][128 * 32];
    __shared__ __align__(16) __hip_bfloat16 Bs[2][128 * 32];

    int bx, by;
    swizzle_bxy(bx, by);

    const int tid  = threadIdx.x;
    const int wv   = tid >> 6;
    const int lane = tid & 63;
    const int ln15 = lane & 15;
    const int lq   = lane >> 4;
    const int wm   = (wv >> 1) * 64;
    const int wn   = (wv & 1) * 64;
    const int row0 = by * 128;
    const int col0 = bx * 128;

    const int sr = wv * 16 + (lane >> 2);
    const int sq = (lane & 3) * 8;

    f32x4 acc[4][4];
#pragma unroll
    for (int i = 0; i < 4; ++i)
#pragma unroll
        for (int j = 0; j < 4; ++j) acc[i][j] = (f32x4){0.f, 0.f, 0.f, 0.f};

    // prologue: stage k0=0 into buffer 0
#pragma unroll
    for (int i = 0; i < 2; ++i) {
        const int r = i * 64 + sr;
        async16(A  + (size_t)(row0 + r) * K + sq, As[0] + r * 32);
        async16(Bt + (size_t)(col0 + r) * K + sq, Bs[0] + r * 32);
    }

    int cur = 0;
    for (int k0 = 0; k0 < K; k0 += 32, cur ^= 1) {
        __syncthreads();   // buf[cur] staged; buf[cur^1] fully consumed
        if (k0 + 32 < K) { // issue next tile's loads; they fly during compute
#pragma unroll
            for (int i = 0; i < 2; ++i) {
                const int r = i * 64 + sr;
                async16(A  + (size_t)(row0 + r) * K + k0 + 32 + sq, As[cur ^ 1] + r * 32);
                async16(Bt + (size_t)(col0 + r) * K + k0 + 32 + sq, Bs[cur ^ 1] + r * 32);
            }
        }

        bf16x8 af[4], bfr[4];
#pragma unroll
        for (int mi = 0; mi < 4; ++mi)
            af[mi] = *(const bf16x8*)&As[cur][(wm + mi * 16 + ln15) * 32 + lq * 8];
#pragma unroll
        for (int ni = 0; ni < 4; ++ni)
            bfr[ni] = *(const bf16x8*)&Bs[cur][(wn + ni * 16 + ln15) * 32 + lq * 8];
#pragma unroll
        for (int mi = 0; mi < 4; ++mi)
#pragma unroll
            for (int ni = 0; ni < 4; ++ni)
                acc[mi][ni] = __builtin_amdgcn_mfma_f32_16x16x32_bf16(
                    af[mi], bfr[ni], acc[mi][ni], 0, 0, 0);
    }

#pragma unroll
    for (int mi = 0; mi < 4; ++mi) {
#pragma unroll
        for (int ni = 0; ni < 4; ++ni) {
            const int gc = col0 + wn + ni * 16 + ln15;
            const float bv = bias[gc];
#pragma unroll
            for (int r = 0; r < 4; ++r) {
                const int gr = row0 + wm + mi * 16 + lq * 4 + r;
                float v = acc[mi][ni][r] + bv;
                if (act == 1) v = gelu_exact(v);
                if (residual) v += residual[(size_t)gr * N + gc];
                if (outBf16)
                    ((__hip_bfloat16*)Cout)[(size_t)gr * N + gc] = __float2bfloat16(v);
                else
                    ((float*)Cout)[(size_t)gr * N + gc] = v;
            }
        }
    }
}

// ---------------------------------------- qkv GEMM with routing epilogue
__global__ __launch_bounds__(256) void mfma_qkv_kernel(
    const __hip_bfloat16* __restrict__ A,
    const __hip_bfloat16* __restrict__ Bt,
    const float* __restrict__ bias,
    __hip_bfloat16* __restrict__ Qb,
    __hip_bfloat16* __restrict__ Kb,
    __hip_bfloat16* __restrict__ Vtb)
{
    const int K = D_MODEL, N = C3;
    __shared__ __align__(16) __hip_bfloat16 As[2][128 * 32];
    __shared__ __align__(16) __hip_bfloat16 Bs[2][128 * 32];

    int bx, by;
    swizzle_bxy(bx, by);

    const int tid  = threadIdx.x;
    const int wv   = tid >> 6;
    const int lane = tid & 63;
    const int ln15 = lane & 15;
    const int lq   = lane >> 4;
    const int wm   = (wv >> 1) * 64;
    const int wn   = (wv & 1) * 64;
    const int row0 = by * 128;
    const int col0 = bx * 128;

    const int sr = wv * 16 + (lane >> 2);
    const int sq = (lane & 3) * 8;

    f32x4 acc[4][4];
#pragma unroll
    for (int i = 0; i < 4; ++i)
#pragma unroll
        for (int j = 0; j < 4; ++j) acc[i][j] = (f32x4){0.f, 0.f, 0.f, 0.f};

#pragma unroll
    for (int i = 0; i < 2; ++i) {
        const int r = i * 64 + sr;
        async16(A  + (size_t)(row0 + r) * K + sq, As[0] + r * 32);
        async16(Bt + (size_t)(col0 + r) * K + sq, Bs[0] + r * 32);
    }

    int cur = 0;
    for (int k0 = 0; k0 < K; k0 += 32, cur ^= 1) {
        __syncthreads();
        if (k0 + 32 < K) {
#pragma unroll
            for (int i = 0; i < 2; ++i) {
                const int r = i * 64 + sr;
                async16(A  + (size_t)(row0 + r) * K + k0 + 32 + sq, As[cur ^ 1] + r * 32);
                async16(Bt + (size_t)(col0 + r) * K + k0 + 32 + sq, Bs[cur ^ 1] + r * 32);
            }
        }

        bf16x8 af[4], bfr[4];
#pragma unroll
        for (int mi = 0; mi < 4; ++mi)
            af[mi] = *(const bf16x8*)&As[cur][(wm + mi * 16 + ln15) * 32 + lq * 8];
#pragma unroll
        for (int ni = 0; ni < 4; ++ni)
            bfr[ni] = *(const bf16x8*)&Bs[cur][(wn + ni * 16 + ln15) * 32 + lq * 8];
#pragma unroll
        for (int mi = 0; mi < 4; ++mi)
#pragma unroll
            for (int ni = 0; ni < 4; ++ni)
                acc[mi][ni] = __builtin_amdgcn_mfma_f32_16x16x32_bf16(
                    af[mi], bfr[ni], acc[mi][ni], 0, 0, 0);
    }

#pragma unroll
    for (int mi = 0; mi < 4; ++mi) {
        const int gr0 = row0 + wm + mi * 16 + lq * 4;   // + r
        const int bb  = gr0 >> 11;
        const int q0  = gr0 & 2047;
#pragma unroll
        for (int ni = 0; ni < 4; ++ni) {
            const int gc  = col0 + wn + ni * 16 + ln15;
            const float bv = bias[gc];
            const int sec = gc >> 10;            // 0:Q 1:K 2:V
            const int hd  = (gc & 1023) >> 6;
            const int d   = gc & 63;
            if (sec == 2) {
                unsigned short u[4];
#pragma unroll
                for (int r = 0; r < 4; ++r) {
                    __hip_bfloat16 e = __float2bfloat16(acc[mi][ni][r] + bv);
                    u[r] = *(unsigned short*)&e;
                }
                uint2 pk;
                pk.x = (unsigned int)u[0] | ((unsigned int)u[1] << 16);
                pk.y = (unsigned int)u[2] | ((unsigned int)u[3] << 16);
                *(uint2*)(Vtb + ((size_t)((bb * N_HEAD + hd) * D_HEAD + d)) * SEQ_T + q0) = pk;
            } else {
                __hip_bfloat16* dst = (sec == 0 ? Qb : Kb)
                    + ((size_t)((bb * N_HEAD + hd) * SEQ_T + q0)) * D_HEAD + d;
#pragma unroll
                for (int r = 0; r < 4; ++r)
                    dst[(size_t)r * D_HEAD] = __float2bfloat16(acc[mi][ni][r] + bv);
            }
        }
    }
}

// ------------------------------------------------- MFMA flash attention v2
#define ATQ 64
#define ATK 128
#define NQT (SEQ_T / ATQ)   // 32
#define KP  72
#define VP  136

__global__ __launch_bounds__(256) void mfma_attn_kernel(
    const __hip_bfloat16* __restrict__ Qb,
    const __hip_bfloat16* __restrict__ Kb,
    const __hip_bfloat16* __restrict__ Vtb,
    __hip_bfloat16* __restrict__ y)
{
    __shared__ __align__(16) __hip_bfloat16 Ks[ATK * KP];
    __shared__ __align__(16) __hip_bfloat16 Vts[D_HEAD * VP];
    __shared__ __align__(16) __hip_bfloat16 Ps[ATQ * VP];

    const int pair = blockIdx.x;
    const int h    = blockIdx.y;
    const int b    = blockIdx.z;
    const int tid  = threadIdx.x;
    const int wv   = tid >> 6;
    const int lane = tid & 63;
    const int ln15 = lane & 15;
    const int lq   = lane >> 4;

    const __hip_bfloat16* Qh = Qb  + (size_t)(b * N_HEAD + h) * SEQ_T * D_HEAD;
    const __hip_bfloat16* Kh = Kb  + (size_t)(b * N_HEAD + h) * SEQ_T * D_HEAD;
    const __hip_bfloat16* Vh = Vtb + (size_t)(b * N_HEAD + h) * D_HEAD * SEQ_T;
    const size_t bT = (size_t)b * SEQ_T;

#pragma unroll 1
    for (int half = 0; half < 2; ++half) {
        const int qt    = half == 0 ? pair : (NQT - 1 - pair);
        const int qbase = qt * ATQ;
        const int ntk   = (qt >> 1) + 1;
        const int qg    = qbase + wv * 16 + ln15;

        bf16x8 qf[2];
#pragma unroll
        for (int kc = 0; kc < 2; ++kc)
            qf[kc] = *(const bf16x8*)(Qh + (size_t)(qbase + wv * 16 + ln15) * D_HEAD
                                      + kc * 32 + lq * 8);

        f32x4 Oacc[4];
#pragma unroll
        for (int dn = 0; dn < 4; ++dn) Oacc[dn] = (f32x4){0.f, 0.f, 0.f, 0.f};
        float m_run = -INFINITY, l_run = 0.f;

        for (int t = 0; t < ntk; ++t) {
            const int kb = t * ATK;
            __syncthreads();
#pragma unroll
            for (int i = 0; i < 4; ++i) {
                const int ch = tid + i * 256;
                const int r = ch >> 3, c8 = (ch & 7) * 8;
                *(bf16x8*)&Ks[r * KP + c8] =
                    *(const bf16x8*)(Kh + (size_t)(kb + r) * D_HEAD + c8);
            }
#pragma unroll
            for (int i = 0; i < 4; ++i) {
                const int ch = tid + i * 256;
                const int r = ch >> 4, c8 = (ch & 15) * 8;
                *(bf16x8*)&Vts[r * VP + c8] =
                    *(const bf16x8*)(Vh + (size_t)r * SEQ_T + kb + c8);
            }
            __syncthreads();

            f32x4 st[8];
#pragma unroll
            for (int jf = 0; jf < 8; ++jf) st[jf] = (f32x4){0.f, 0.f, 0.f, 0.f};
#pragma unroll
            for (int jf = 0; jf < 8; ++jf) {
                const bf16x8 kf0 = *(const bf16x8*)&Ks[(jf * 16 + ln15) * KP + lq * 8];
                const bf16x8 kf1 = *(const bf16x8*)&Ks[(jf * 16 + ln15) * KP + 32 + lq * 8];
                st[jf] = __builtin_amdgcn_mfma_f32_16x16x32_bf16(kf0, qf[0], st[jf], 0, 0, 0);
                st[jf] = __builtin_amdgcn_mfma_f32_16x16x32_bf16(kf1, qf[1], st[jf], 0, 0, 0);
            }

            const bool last = (t == ntk - 1);
#pragma unroll
            for (int jf = 0; jf < 8; ++jf)
#pragma unroll
                for (int r = 0; r < 4; ++r) {
                    float v = st[jf][r] * 0.125f;
                    if (last && (kb + jf * 16 + lq * 4 + r) > qg) v = -INFINITY;
                    st[jf][r] = v;
                }

            float tmax = st[0][0];
#pragma unroll
            for (int jf = 0; jf < 8; ++jf)
#pragma unroll
                for (int r = 0; r < 4; ++r) tmax = fmaxf(tmax, st[jf][r]);
            tmax = fmaxf(tmax, __shfl_xor(tmax, 16));
            tmax = fmaxf(tmax, __shfl_xor(tmax, 32));
            const float mnew  = fmaxf(m_run, tmax);
            const float alpha = __expf(m_run - mnew);
            float psum = 0.f;
#pragma unroll
            for (int jf = 0; jf < 8; ++jf)
#pragma unroll
                for (int r = 0; r < 4; ++r) {
                    const float p = __expf(st[jf][r] - mnew);
                    st[jf][r] = p;
                    psum += p;
                }
            psum += __shfl_xor(psum, 16);
            psum += __shfl_xor(psum, 32);
            l_run = alpha * l_run + psum;
            m_run = mnew;

            float a4[4];
#pragma unroll
            for (int r = 0; r < 4; ++r) a4[r] = __shfl(alpha, lq * 4 + r);
#pragma unroll
            for (int dn = 0; dn < 4; ++dn)
#pragma unroll
                for (int r = 0; r < 4; ++r) Oacc[dn][r] *= a4[r];

#pragma unroll
            for (int jf = 0; jf < 8; ++jf) {
                __hip_bfloat162 p01 = __float22bfloat162_rn(make_float2(st[jf][0], st[jf][1]));
                __hip_bfloat162 p23 = __float22bfloat162_rn(make_float2(st[jf][2], st[jf][3]));
                uint2 pk;
                pk.x = *(unsigned int*)&p01;
                pk.y = *(unsigned int*)&p23;
                *(uint2*)&Ps[(wv * 16 + ln15) * VP + jf * 16 + lq * 4] = pk;
            }

            bf16x8 pf[4];
#pragma unroll
            for (int jc = 0; jc < 4; ++jc)
                pf[jc] = *(const bf16x8*)&Ps[(wv * 16 + ln15) * VP + jc * 32 + lq * 8];
#pragma unroll
            for (int dn = 0; dn < 4; ++dn) {
#pragma unroll
                for (int jc = 0; jc < 4; ++jc) {
                    const bf16x8 vf = *(const bf16x8*)&Vts[(dn * 16 + ln15) * VP + jc * 32 + lq * 8];
                    Oacc[dn] = __builtin_amdgcn_mfma_f32_16x16x32_bf16(
                        pf[jc], vf, Oacc[dn], 0, 0, 0);
                }
            }
        }

        float il[4];
#pragma unroll
        for (int r = 0; r < 4; ++r) il[r] = 1.0f / __shfl(l_run, lq * 4 + r);
#pragma unroll
        for (int dn = 0; dn < 4; ++dn)
#pragma unroll
            for (int r = 0; r < 4; ++r)
                Ps[(wv * 16 + lq * 4 + r) * VP + dn * 16 + ln15] =
                    __float2bfloat16(Oacc[dn][r] * il[r]);
        const int r2 = lane >> 3, c8 = (lane & 7) * 8;
#pragma unroll
        for (int i = 0; i < 2; ++i) {
            const int row = wv * 16 + r2 + 8 * i;
            const bf16x8 val = *(const bf16x8*)&Ps[row * VP + c8];
            *(bf16x8*)(y + (bT + qbase + row) * D_MODEL + h * D_HEAD + c8) = val;
        }
    }
}

// ------------------------------------------------------------------ launch
extern "C" void kernel_launch(void* const* d_in, const int* in_sizes, int n_in,
                              void* d_out, int out_size, void* d_ws, size_t ws_size,
                              hipStream_t stream)
{
    const float* x      = (const float*)d_in[0];
    const float* ln1_w  = (const float*)d_in[1];
    const float* ln1_b  = (const float*)d_in[2];
    const float* attn_w = (const float*)d_in[3];
    const float* attn_b = (const float*)d_in[4];
    const float* proj_w = (const float*)d_in[5];
    const float* proj_b = (const float*)d_in[6];
    const float* ln2_w  = (const float*)d_in[7];
    const float* ln2_b  = (const float*)d_in[8];
    const float* fc_w   = (const float*)d_in[9];
    const float* fc_b   = (const float*)d_in[10];
    const float* fc2_w  = (const float*)d_in[11];
    const float* fc2_b  = (const float*)d_in[12];
    float* out = (float*)d_out;

    char* ws = (char*)d_ws;
    __hip_bfloat16* Qb      = (__hip_bfloat16*)(ws);
    __hip_bfloat16* Kb      = (__hip_bfloat16*)(ws + (size_t)8  * 1024 * 1024);
    __hip_bfloat16* Vtb     = (__hip_bfloat16*)(ws + (size_t)16 * 1024 * 1024);
    __hip_bfloat16* h_bf    = (__hip_bfloat16*)(ws);
    __hip_bfloat16* ln_buf  = (__hip_bfloat16*)(ws + (size_t)32 * 1024 * 1024);
    __hip_bfloat16* y_buf   = (__hip_bfloat16*)(ws + (size_t)40 * 1024 * 1024);
    float*          xmid    = (float*)(ws + (size_t)48 * 1024 * 1024);
    __hip_bfloat16* attn_wt = (__hip_bfloat16*)(ws + (size_t)64 * 1024 * 1024);
    __hip_bfloat16* proj_wt = (__hip_bfloat16*)(ws + (size_t)70 * 1024 * 1024);
    __hip_bfloat16* fc_wt   = (__hip_bfloat16*)(ws + (size_t)72 * 1024 * 1024);
    __hip_bfloat16* fc2_wt  = (__hip_bfloat16*)(ws + (size_t)80 * 1024 * 1024);

    dim3 blk256(256);

    // 0. all weight transposes in one launch (fp32 [K,N] -> bf16 [N,K])
    transpose_all_kernel<<<dim3(12288), blk256, 0, stream>>>(
        attn_w, proj_w, fc_w, fc2_w, attn_wt, proj_wt, fc_wt, fc2_wt);

    // 1. ln1(x) -> ln_buf (bf16)
    ln_kernel<<<dim3(NROWS), blk256, 0, stream>>>(x, ln1_w, ln1_b, ln_buf, D_MODEL);

    // 2. qkv GEMM -> Qb/Kb/Vtb (bf16, per-head layouts)
    mfma_qkv_kernel<<<dim3(C3 / 128, NROWS / 128), blk256, 0, stream>>>(
        ln_buf, attn_wt, attn_b, Qb, Kb, Vtb);

    // 3. MFMA flash attention -> y_buf (bf16)
    mfma_attn_kernel<<<dim3(NQT / 2, N_HEAD, BATCH), blk256, 0, stream>>>(
        Qb, Kb, Vtb, y_buf);

    // 4. xmid = x + y_buf @ proj_w + proj_b  (fp32)
    mfma_gemm_kernel<<<dim3(D_MODEL / 128, NROWS / 128), blk256, 0, stream>>>(
        y_buf, proj_wt, proj_b, x, xmid, NROWS, D_MODEL, D_MODEL, 0, 0);

    // 5. ln2(xmid) -> ln_buf (bf16)
    ln_kernel<<<dim3(NROWS), blk256, 0, stream>>>(xmid, ln2_w, ln2_b, ln_buf, D_MODEL);

    // 6. h = gelu(ln_buf @ fc_w + fc_b) -> bf16
    mfma_gemm_kernel<<<dim3(D_FF / 128, NROWS / 128), blk256, 0, stream>>>(
        ln_buf, fc_wt, fc_b, nullptr, h_bf, NROWS, D_FF, D_MODEL, 1, 1);

    // 7. out = xmid + h @ fc2_w + fc2_b  (fp32)
    mfma_gemm_kernel<<<dim3(D_MODEL / 128, NROWS / 128), blk256, 0, stream>>>(
        h_bf, fc2_wt, fc2_b, xmid, out, NROWS, D_MODEL, D_FF, 0, 0);
}

// Round 8
// 419.183 us; speedup vs baseline: 10.4388x; 1.0920x over previous
//
#include <hip/hip_runtime.h>
#include <hip/hip_bf16.h>
#include <math.h>

// Transformer block. Round 8: 4-stage pipelined MFMA GEMMs using raw
// s_barrier + manual s_waitcnt vmcnt(4) (AITER-style, never vmcnt(0) in
// steady state). Pipeline core is a device function (Round 7 macro version
// failed to compile: #pragma inside macro args).
// D_MODEL=1024, N_HEAD=16, D_HEAD=64, EXP=4, B=2, T=2048, EPS=1e-5

#define D_MODEL 1024
#define N_HEAD  16
#define D_HEAD  64
#define SEQ_T   2048
#define BATCH   2
#define NROWS   (BATCH * SEQ_T)   // 4096
#define C3      (3 * D_MODEL)     // 3072
#define D_FF    (4 * D_MODEL)     // 4096

typedef __bf16 bf16x8 __attribute__((ext_vector_type(8)));
typedef float  f32x4  __attribute__((ext_vector_type(4)));

// s_waitcnt imm: vmcnt[3:0]=bits3:0, expcnt=bits6:4, lgkmcnt=bits11:8.
// 0x0F74 = vmcnt(4) only. 0x0F70 = vmcnt(0) only.
#define WAIT_VM4() __builtin_amdgcn_s_waitcnt(0x0F74)
#define WAIT_VM0() __builtin_amdgcn_s_waitcnt(0x0F70)

// ---------------------------------------------------------------- LayerNorm
__global__ __launch_bounds__(256) void ln_kernel(
    const float* __restrict__ in, const float* __restrict__ w,
    const float* __restrict__ b, __hip_bfloat16* __restrict__ out, int D)
{
    const int row = blockIdx.x;
    const int tid = threadIdx.x;
    const float* x = in + (size_t)row * D;

    float s = 0.f, s2 = 0.f;
    for (int i = tid; i < D; i += 256) {
        float v = x[i];
        s += v; s2 += v * v;
    }
    __shared__ float rs[256], rs2[256];
    rs[tid] = s; rs2[tid] = s2;
    __syncthreads();
    for (int off = 128; off > 0; off >>= 1) {
        if (tid < off) { rs[tid] += rs[tid + off]; rs2[tid] += rs2[tid + off]; }
        __syncthreads();
    }
    const float mu   = rs[0] / D;
    const float var  = rs2[0] / D - mu * mu;
    const float rstd = rsqrtf(var + 1e-5f);

    __hip_bfloat16* o = out + (size_t)row * D;
    for (int i = tid; i < D; i += 256)
        o[i] = __float2bfloat16((x[i] - mu) * rstd * w[i] + b[i]);
}

// -------------------------------- merged weight transpose + bf16 cast (x4)
__global__ __launch_bounds__(256) void transpose_all_kernel(
    const float* __restrict__ attn_w, const float* __restrict__ proj_w,
    const float* __restrict__ fc_w,   const float* __restrict__ fc2_w,
    __hip_bfloat16* __restrict__ attn_wt, __hip_bfloat16* __restrict__ proj_wt,
    __hip_bfloat16* __restrict__ fc_wt,   __hip_bfloat16* __restrict__ fc2_wt)
{
    __shared__ float t[32][33];
    int tb = blockIdx.x;
    const float* W; __hip_bfloat16* Wt; int K, N;
    if (tb < 3072)      { W = attn_w; Wt = attn_wt; K = D_MODEL; N = C3; }
    else if (tb < 4096) { tb -= 3072; W = proj_w; Wt = proj_wt; K = D_MODEL; N = D_MODEL; }
    else if (tb < 8192) { tb -= 4096; W = fc_w;   Wt = fc_wt;   K = D_MODEL; N = D_FF; }
    else                { tb -= 8192; W = fc2_w;  Wt = fc2_wt;  K = D_FF;    N = D_MODEL; }
    const int ntx = N >> 5;
    const int k0 = (tb / ntx) * 32;
    const int n0 = (tb % ntx) * 32;

    const int tx = threadIdx.x & 31;
    const int ty = threadIdx.x >> 5;
#pragma unroll
    for (int i = 0; i < 4; ++i)
        t[ty + 8 * i][tx] = W[(size_t)(k0 + ty + 8 * i) * N + n0 + tx];
    __syncthreads();
#pragma unroll
    for (int i = 0; i < 4; ++i)
        Wt[(size_t)(n0 + ty + 8 * i) * K + k0 + tx] =
            __float2bfloat16(t[tx][ty + 8 * i]);
}

// ----------------------------------------------------------- bf16 MFMA GEMM
__device__ __forceinline__ void async16(const __hip_bfloat16* g, __hip_bfloat16* l)
{
    __builtin_amdgcn_global_load_lds(
        (const __attribute__((address_space(1))) void*)g,
        (__attribute__((address_space(3))) void*)l, 16, 0, 0);
}

__device__ __forceinline__ float gelu_exact(float v)
{
    return 0.5f * v * (1.0f + erff(v * 0.70710678118654752f));
}

// L2 swizzle: walk 4 row-tiles before advancing a column (nby % 4 == 0 here).
__device__ __forceinline__ void swizzle_bxy(int& bx, int& by)
{
    const int nbx = gridDim.x;
    const int lin = blockIdx.y * nbx + blockIdx.x;
    const int stripe = 4 * nbx;
    const int s = lin / stripe;
    const int rem = lin - s * stripe;
    by = s * 4 + (rem & 3);
    bx = rem >> 2;
}

// 4-stage pipelined 128x128xK MFMA core. nt = K/32 must be a multiple of 4
// (K=1024 -> 32, K=4096 -> 128). Raw s_barrier + manual vmcnt(4): tile t's
// 4 loads complete while t+1's 4 stay in flight; prefetch distance 2.
// Reuse-distance-4 buffers make the single barrier race-free.
__device__ __forceinline__ void gemm_pipeline_core(
    const __hip_bfloat16* __restrict__ A,
    const __hip_bfloat16* __restrict__ Bt,
    int K, int row0, int col0,
    int wm, int wn, int ln15, int lq,
    f32x4 (&acc)[4][4])
{
    __shared__ __align__(16) __hip_bfloat16 As0[4096], As1[4096],
                                            As2[4096], As3[4096];
    __shared__ __align__(16) __hip_bfloat16 Bs0[4096], Bs1[4096],
                                            Bs2[4096], Bs3[4096];
    __hip_bfloat16* const Ab[4] = {As0, As1, As2, As3};
    __hip_bfloat16* const Bb[4] = {Bs0, Bs1, Bs2, Bs3};

    const int tid  = threadIdx.x;
    const int wv   = tid >> 6;
    const int lane = tid & 63;
    const int sr = wv * 16 + (lane >> 2);
    const int sq = (lane & 3) * 8;

    auto stage = [&](int kt, __hip_bfloat16* as, __hip_bfloat16* bs) {
        const int k0 = kt * 32;
#pragma unroll
        for (int i = 0; i < 2; ++i) {
            const int r = i * 64 + sr;
            async16(A  + (size_t)(row0 + r) * K + k0 + sq, as + r * 32);
            async16(Bt + (size_t)(col0 + r) * K + k0 + sq, bs + r * 32);
        }
    };

#pragma unroll
    for (int i = 0; i < 4; ++i)
#pragma unroll
        for (int j = 0; j < 4; ++j) acc[i][j] = (f32x4){0.f, 0.f, 0.f, 0.f};

    stage(0, Ab[0], Bb[0]);
    stage(1, Ab[1], Bb[1]);

    const int nt = K >> 5;
    for (int t0 = 0; t0 < nt; t0 += 4) {
#pragma unroll
        for (int u = 0; u < 4; ++u) {
            const int t = t0 + u;
            if (t + 1 < nt) WAIT_VM4(); else WAIT_VM0();
            __builtin_amdgcn_s_barrier();
            const __hip_bfloat16* as = Ab[u];
            const __hip_bfloat16* bs = Bb[u];
            bf16x8 af[4], bfr[4];
#pragma unroll
            for (int mi = 0; mi < 4; ++mi)
                af[mi] = *(const bf16x8*)&as[(wm + mi * 16 + ln15) * 32 + lq * 8];
#pragma unroll
            for (int ni = 0; ni < 4; ++ni)
                bfr[ni] = *(const bf16x8*)&bs[(wn + ni * 16 + ln15) * 32 + lq * 8];
#pragma unroll
            for (int mi = 0; mi < 4; ++mi)
#pragma unroll
                for (int ni = 0; ni < 4; ++ni)
                    acc[mi][ni] = __builtin_amdgcn_mfma_f32_16x16x32_bf16(
                        af[mi], bfr[ni], acc[mi][ni], 0, 0, 0);
            if (t + 2 < nt) stage(t + 2, Ab[(u + 2) & 3], Bb[(u + 2) & 3]);
        }
    }
}

__global__ __launch_bounds__(256) void mfma_gemm_kernel(
    const __hip_bfloat16* __restrict__ A,   // [M,K]
    const __hip_bfloat16* __restrict__ Bt,  // [N,K]
    const float* __restrict__ bias,         // [N]
    const float* __restrict__ residual,     // [M,N] or null
    void* __restrict__ Cout,                // [M,N] fp32 or bf16
    int M, int N, int K, int act, int outBf16)
{
    int bx, by;
    swizzle_bxy(bx, by);
    const int tid  = threadIdx.x;
    const int wv   = tid >> 6;
    const int lane = tid & 63;
    const int ln15 = lane & 15;
    const int lq   = lane >> 4;
    const int wm   = (wv >> 1) * 64;
    const int wn   = (wv & 1) * 64;
    const int row0 = by * 128;
    const int col0 = bx * 128;

    f32x4 acc[4][4];
    gemm_pipeline_core(A, Bt, K, row0, col0, wm, wn, ln15, lq, acc);

#pragma unroll
    for (int mi = 0; mi < 4; ++mi) {
#pragma unroll
        for (int ni = 0; ni < 4; ++ni) {
            const int gc = col0 + wn + ni * 16 + ln15;
            const float bv = bias[gc];
#pragma unroll
            for (int r = 0; r < 4; ++r) {
                const int gr = row0 + wm + mi * 16 + lq * 4 + r;
                float v = acc[mi][ni][r] + bv;
                if (act == 1) v = gelu_exact(v);
                if (residual) v += residual[(size_t)gr * N + gc];
                if (outBf16)
                    ((__hip_bfloat16*)Cout)[(size_t)gr * N + gc] = __float2bfloat16(v);
                else
                    ((float*)Cout)[(size_t)gr * N + gc] = v;
            }
        }
    }
}

// ---------------------------------------- qkv GEMM with routing epilogue
__global__ __launch_bounds__(256) void mfma_qkv_kernel(
    const __hip_bfloat16* __restrict__ A,
    const __hip_bfloat16* __restrict__ Bt,
    const float* __restrict__ bias,
    __hip_bfloat16* __restrict__ Qb,
    __hip_bfloat16* __restrict__ Kb,
    __hip_bfloat16* __restrict__ Vtb)
{
    const int K = D_MODEL;
    int bx, by;
    swizzle_bxy(bx, by);
    const int tid  = threadIdx.x;
    const int wv   = tid >> 6;
    const int lane = tid & 63;
    const int ln15 = lane & 15;
    const int lq   = lane >> 4;
    const int wm   = (wv >> 1) * 64;
    const int wn   = (wv & 1) * 64;
    const int row0 = by * 128;
    const int col0 = bx * 128;

    f32x4 acc[4][4];
    gemm_pipeline_core(A, Bt, K, row0, col0, wm, wn, ln15, lq, acc);

#pragma unroll
    for (int mi = 0; mi < 4; ++mi) {
        const int gr0 = row0 + wm + mi * 16 + lq * 4;   // + r
        const int bb  = gr0 >> 11;
        const int q0  = gr0 & 2047;
#pragma unroll
        for (int ni = 0; ni < 4; ++ni) {
            const int gc  = col0 + wn + ni * 16 + ln15;
            const float bv = bias[gc];
            const int sec = gc >> 10;            // 0:Q 1:K 2:V
            const int hd  = (gc & 1023) >> 6;
            const int d   = gc & 63;
            if (sec == 2) {
                unsigned short u[4];
#pragma unroll
                for (int r = 0; r < 4; ++r) {
                    __hip_bfloat16 e = __float2bfloat16(acc[mi][ni][r] + bv);
                    u[r] = *(unsigned short*)&e;
                }
                uint2 pk;
                pk.x = (unsigned int)u[0] | ((unsigned int)u[1] << 16);
                pk.y = (unsigned int)u[2] | ((unsigned int)u[3] << 16);
                *(uint2*)(Vtb + ((size_t)((bb * N_HEAD + hd) * D_HEAD + d)) * SEQ_T + q0) = pk;
            } else {
                __hip_bfloat16* dst = (sec == 0 ? Qb : Kb)
                    + ((size_t)((bb * N_HEAD + hd) * SEQ_T + q0)) * D_HEAD + d;
#pragma unroll
                for (int r = 0; r < 4; ++r)
                    dst[(size_t)r * D_HEAD] = __float2bfloat16(acc[mi][ni][r] + bv);
            }
        }
    }
}

// ------------------------------------------------- MFMA flash attention v2
#define ATQ 64
#define ATK 128
#define NQT (SEQ_T / ATQ)   // 32
#define KP  72
#define VP  136

__global__ __launch_bounds__(256) void mfma_attn_kernel(
    const __hip_bfloat16* __restrict__ Qb,
    const __hip_bfloat16* __restrict__ Kb,
    const __hip_bfloat16* __restrict__ Vtb,
    __hip_bfloat16* __restrict__ y)
{
    __shared__ __align__(16) __hip_bfloat16 Ks[ATK * KP];
    __shared__ __align__(16) __hip_bfloat16 Vts[D_HEAD * VP];
    __shared__ __align__(16) __hip_bfloat16 Ps[ATQ * VP];

    const int pair = blockIdx.x;
    const int h    = blockIdx.y;
    const int b    = blockIdx.z;
    const int tid  = threadIdx.x;
    const int wv   = tid >> 6;
    const int lane = tid & 63;
    const int ln15 = lane & 15;
    const int lq   = lane >> 4;

    const __hip_bfloat16* Qh = Qb  + (size_t)(b * N_HEAD + h) * SEQ_T * D_HEAD;
    const __hip_bfloat16* Kh = Kb  + (size_t)(b * N_HEAD + h) * SEQ_T * D_HEAD;
    const __hip_bfloat16* Vh = Vtb + (size_t)(b * N_HEAD + h) * D_HEAD * SEQ_T;
    const size_t bT = (size_t)b * SEQ_T;

#pragma unroll 1
    for (int half = 0; half < 2; ++half) {
        const int qt    = half == 0 ? pair : (NQT - 1 - pair);
        const int qbase = qt * ATQ;
        const int ntk   = (qt >> 1) + 1;
        const int qg    = qbase + wv * 16 + ln15;

        bf16x8 qf[2];
#pragma unroll
        for (int kc = 0; kc < 2; ++kc)
            qf[kc] = *(const bf16x8*)(Qh + (size_t)(qbase + wv * 16 + ln15) * D_HEAD
                                      + kc * 32 + lq * 8);

        f32x4 Oacc[4];
#pragma unroll
        for (int dn = 0; dn < 4; ++dn) Oacc[dn] = (f32x4){0.f, 0.f, 0.f, 0.f};
        float m_run = -INFINITY, l_run = 0.f;

        for (int t = 0; t < ntk; ++t) {
            const int kb = t * ATK;
            __syncthreads();
#pragma unroll
            for (int i = 0; i < 4; ++i) {
                const int ch = tid + i * 256;
                const int r = ch >> 3, c8 = (ch & 7) * 8;
                *(bf16x8*)&Ks[r * KP + c8] =
                    *(const bf16x8*)(Kh + (size_t)(kb + r) * D_HEAD + c8);
            }
#pragma unroll
            for (int i = 0; i < 4; ++i) {
                const int ch = tid + i * 256;
                const int r = ch >> 4, c8 = (ch & 15) * 8;
                *(bf16x8*)&Vts[r * VP + c8] =
                    *(const bf16x8*)(Vh + (size_t)r * SEQ_T + kb + c8);
            }
            __syncthreads();

            f32x4 st[8];
#pragma unroll
            for (int jf = 0; jf < 8; ++jf) st[jf] = (f32x4){0.f, 0.f, 0.f, 0.f};
#pragma unroll
            for (int jf = 0; jf < 8; ++jf) {
                const bf16x8 kf0 = *(const bf16x8*)&Ks[(jf * 16 + ln15) * KP + lq * 8];
                const bf16x8 kf1 = *(const bf16x8*)&Ks[(jf * 16 + ln15) * KP + 32 + lq * 8];
                st[jf] = __builtin_amdgcn_mfma_f32_16x16x32_bf16(kf0, qf[0], st[jf], 0, 0, 0);
                st[jf] = __builtin_amdgcn_mfma_f32_16x16x32_bf16(kf1, qf[1], st[jf], 0, 0, 0);
            }

            const bool last = (t == ntk - 1);
#pragma unroll
            for (int jf = 0; jf < 8; ++jf)
#pragma unroll
                for (int r = 0; r < 4; ++r) {
                    float v = st[jf][r] * 0.125f;
                    if (last && (kb + jf * 16 + lq * 4 + r) > qg) v = -INFINITY;
                    st[jf][r] = v;
                }

            float tmax = st[0][0];
#pragma unroll
            for (int jf = 0; jf < 8; ++jf)
#pragma unroll
                for (int r = 0; r < 4; ++r) tmax = fmaxf(tmax, st[jf][r]);
            tmax = fmaxf(tmax, __shfl_xor(tmax, 16));
            tmax = fmaxf(tmax, __shfl_xor(tmax, 32));
            const float mnew  = fmaxf(m_run, tmax);
            const float alpha = __expf(m_run - mnew);
            float psum = 0.f;
#pragma unroll
            for (int jf = 0; jf < 8; ++jf)
#pragma unroll
                for (int r = 0; r < 4; ++r) {
                    const float p = __expf(st[jf][r] - mnew);
                    st[jf][r] = p;
                    psum += p;
                }
            psum += __shfl_xor(psum, 16);
            psum += __shfl_xor(psum, 32);
            l_run = alpha * l_run + psum;
            m_run = mnew;

            float a4[4];
#pragma unroll
            for (int r = 0; r < 4; ++r) a4[r] = __shfl(alpha, lq * 4 + r);
#pragma unroll
            for (int dn = 0; dn < 4; ++dn)
#pragma unroll
                for (int r = 0; r < 4; ++r) Oacc[dn][r] *= a4[r];

#pragma unroll
            for (int jf = 0; jf < 8; ++jf) {
                __hip_bfloat162 p01 = __float22bfloat162_rn(make_float2(st[jf][0], st[jf][1]));
                __hip_bfloat162 p23 = __float22bfloat162_rn(make_float2(st[jf][2], st[jf][3]));
                uint2 pk;
                pk.x = *(unsigned int*)&p01;
                pk.y = *(unsigned int*)&p23;
                *(uint2*)&Ps[(wv * 16 + ln15) * VP + jf * 16 + lq * 4] = pk;
            }

            bf16x8 pf[4];
#pragma unroll
            for (int jc = 0; jc < 4; ++jc)
                pf[jc] = *(const bf16x8*)&Ps[(wv * 16 + ln15) * VP + jc * 32 + lq * 8];
#pragma unroll
            for (int dn = 0; dn < 4; ++dn) {
#pragma unroll
                for (int jc = 0; jc < 4; ++jc) {
                    const bf16x8 vf = *(const bf16x8*)&Vts[(dn * 16 + ln15) * VP + jc * 32 + lq * 8];
                    Oacc[dn] = __builtin_amdgcn_mfma_f32_16x16x32_bf16(
                        pf[jc], vf, Oacc[dn], 0, 0, 0);
                }
            }
        }

        float il[4];
#pragma unroll
        for (int r = 0; r < 4; ++r) il[r] = 1.0f / __shfl(l_run, lq * 4 + r);
#pragma unroll
        for (int dn = 0; dn < 4; ++dn)
#pragma unroll
            for (int r = 0; r < 4; ++r)
                Ps[(wv * 16 + lq * 4 + r) * VP + dn * 16 + ln15] =
                    __float2bfloat16(Oacc[dn][r] * il[r]);
        const int r2 = lane >> 3, c8 = (lane & 7) * 8;
#pragma unroll
        for (int i = 0; i < 2; ++i) {
            const int row = wv * 16 + r2 + 8 * i;
            const bf16x8 val = *(const bf16x8*)&Ps[row * VP + c8];
            *(bf16x8*)(y + (bT + qbase + row) * D_MODEL + h * D_HEAD + c8) = val;
        }
    }
}

// ------------------------------------------------------------------ launch
extern "C" void kernel_launch(void* const* d_in, const int* in_sizes, int n_in,
                              void* d_out, int out_size, void* d_ws, size_t ws_size,
                              hipStream_t stream)
{
    const float* x      = (const float*)d_in[0];
    const float* ln1_w  = (const float*)d_in[1];
    const float* ln1_b  = (const float*)d_in[2];
    const float* attn_w = (const float*)d_in[3];
    const float* attn_b = (const float*)d_in[4];
    const float* proj_w = (const float*)d_in[5];
    const float* proj_b = (const float*)d_in[6];
    const float* ln2_w  = (const float*)d_in[7];
    const float* ln2_b  = (const float*)d_in[8];
    const float* fc_w   = (const float*)d_in[9];
    const float* fc_b   = (const float*)d_in[10];
    const float* fc2_w  = (const float*)d_in[11];
    const float* fc2_b  = (const float*)d_in[12];
    float* out = (float*)d_out;

    char* ws = (char*)d_ws;
    __hip_bfloat16* Qb      = (__hip_bfloat16*)(ws);
    __hip_bfloat16* Kb      = (__hip_bfloat16*)(ws + (size_t)8  * 1024 * 1024);
    __hip_bfloat16* Vtb     = (__hip_bfloat16*)(ws + (size_t)16 * 1024 * 1024);
    __hip_bfloat16* h_bf    = (__hip_bfloat16*)(ws);
    __hip_bfloat16* ln_buf  = (__hip_bfloat16*)(ws + (size_t)32 * 1024 * 1024);
    __hip_bfloat16* y_buf   = (__hip_bfloat16*)(ws + (size_t)40 * 1024 * 1024);
    float*          xmid    = (float*)(ws + (size_t)48 * 1024 * 1024);
    __hip_bfloat16* attn_wt = (__hip_bfloat16*)(ws + (size_t)64 * 1024 * 1024);
    __hip_bfloat16* proj_wt = (__hip_bfloat16*)(ws + (size_t)70 * 1024 * 1024);
    __hip_bfloat16* fc_wt   = (__hip_bfloat16*)(ws + (size_t)72 * 1024 * 1024);
    __hip_bfloat16* fc2_wt  = (__hip_bfloat16*)(ws + (size_t)80 * 1024 * 1024);

    dim3 blk256(256);

    // 0. all weight transposes in one launch (fp32 [K,N] -> bf16 [N,K])
    transpose_all_kernel<<<dim3(12288), blk256, 0, stream>>>(
        attn_w, proj_w, fc_w, fc2_w, attn_wt, proj_wt, fc_wt, fc2_wt);

    // 1. ln1(x) -> ln_buf (bf16)
    ln_kernel<<<dim3(NROWS), blk256, 0, stream>>>(x, ln1_w, ln1_b, ln_buf, D_MODEL);

    // 2. qkv GEMM -> Qb/Kb/Vtb (bf16, per-head layouts)
    mfma_qkv_kernel<<<dim3(C3 / 128, NROWS / 128), blk256, 0, stream>>>(
        ln_buf, attn_wt, attn_b, Qb, Kb, Vtb);

    // 3. MFMA flash attention -> y_buf (bf16)
    mfma_attn_kernel<<<dim3(NQT / 2, N_HEAD, BATCH), blk256, 0, stream>>>(
        Qb, Kb, Vtb, y_buf);

    // 4. xmid = x + y_buf @ proj_w + proj_b  (fp32)
    mfma_gemm_kernel<<<dim3(D_MODEL / 128, NROWS / 128), blk256, 0, stream>>>(
        y_buf, proj_wt, proj_b, x, xmid, NROWS, D_MODEL, D_MODEL, 0, 0);

    // 5. ln2(xmid) -> ln_buf (bf16)
    ln_kernel<<<dim3(NROWS), blk256, 0, stream>>>(xmid, ln2_w, ln2_b, ln_buf, D_MODEL);

    // 6. h = gelu(ln_buf @ fc_w + fc_b) -> bf16
    mfma_gemm_kernel<<<dim3(D_FF / 128, NROWS / 128), blk256, 0, stream>>>(
        ln_buf, fc_wt, fc_b, nullptr, h_bf, NROWS, D_FF, D_MODEL, 1, 1);

    // 7. out = xmid + h @ fc2_w + fc2_b  (fp32)
    mfma_gemm_kernel<<<dim3(D_MODEL / 128, NROWS / 128), blk256, 0, stream>>>(
        h_bf, fc2_wt, fc2_b, xmid, out, NROWS, D_MODEL, D_FF, 0, 0);
}

// Round 9
// 417.884 us; speedup vs baseline: 10.4712x; 1.0031x over previous
//
#include <hip/hip_runtime.h>
#include <hip/hip_bf16.h>
#include <math.h>

// Transformer block. Round 9: wide-tile (256x128 block, 128x64 wave) pipelined
// GEMM for qkv + fc1 (flop/LDS-byte 16 -> 42.7, breaking the LDS/MFMA parity
// that capped MfmaUtil ~20%). proj/fc2 keep the Round-8 4-deep vmcnt(4) core.
// D_MODEL=1024, N_HEAD=16, D_HEAD=64, EXP=4, B=2, T=2048, EPS=1e-5

#define D_MODEL 1024
#define N_HEAD  16
#define D_HEAD  64
#define SEQ_T   2048
#define BATCH   2
#define NROWS   (BATCH * SEQ_T)   // 4096
#define C3      (3 * D_MODEL)     // 3072
#define D_FF    (4 * D_MODEL)     // 4096

typedef __bf16 bf16x8 __attribute__((ext_vector_type(8)));
typedef float  f32x4  __attribute__((ext_vector_type(4)));

// s_waitcnt imm: vmcnt[3:0]=bits3:0, expcnt=bits6:4, lgkmcnt=bits11:8.
#define WAIT_VM6() __builtin_amdgcn_s_waitcnt(0x0F76)
#define WAIT_VM4() __builtin_amdgcn_s_waitcnt(0x0F74)
#define WAIT_VM0() __builtin_amdgcn_s_waitcnt(0x0F70)

// ---------------------------------------------------------------- LayerNorm
__global__ __launch_bounds__(256) void ln_kernel(
    const float* __restrict__ in, const float* __restrict__ w,
    const float* __restrict__ b, __hip_bfloat16* __restrict__ out, int D)
{
    const int row = blockIdx.x;
    const int tid = threadIdx.x;
    const float* x = in + (size_t)row * D;

    float s = 0.f, s2 = 0.f;
    for (int i = tid; i < D; i += 256) {
        float v = x[i];
        s += v; s2 += v * v;
    }
    __shared__ float rs[256], rs2[256];
    rs[tid] = s; rs2[tid] = s2;
    __syncthreads();
    for (int off = 128; off > 0; off >>= 1) {
        if (tid < off) { rs[tid] += rs[tid + off]; rs2[tid] += rs2[tid + off]; }
        __syncthreads();
    }
    const float mu   = rs[0] / D;
    const float var  = rs2[0] / D - mu * mu;
    const float rstd = rsqrtf(var + 1e-5f);

    __hip_bfloat16* o = out + (size_t)row * D;
    for (int i = tid; i < D; i += 256)
        o[i] = __float2bfloat16((x[i] - mu) * rstd * w[i] + b[i]);
}

// -------------------------------- merged weight transpose + bf16 cast (x4)
__global__ __launch_bounds__(256) void transpose_all_kernel(
    const float* __restrict__ attn_w, const float* __restrict__ proj_w,
    const float* __restrict__ fc_w,   const float* __restrict__ fc2_w,
    __hip_bfloat16* __restrict__ attn_wt, __hip_bfloat16* __restrict__ proj_wt,
    __hip_bfloat16* __restrict__ fc_wt,   __hip_bfloat16* __restrict__ fc2_wt)
{
    __shared__ float t[32][33];
    int tb = blockIdx.x;
    const float* W; __hip_bfloat16* Wt; int K, N;
    if (tb < 3072)      { W = attn_w; Wt = attn_wt; K = D_MODEL; N = C3; }
    else if (tb < 4096) { tb -= 3072; W = proj_w; Wt = proj_wt; K = D_MODEL; N = D_MODEL; }
    else if (tb < 8192) { tb -= 4096; W = fc_w;   Wt = fc_wt;   K = D_MODEL; N = D_FF; }
    else                { tb -= 8192; W = fc2_w;  Wt = fc2_wt;  K = D_FF;    N = D_MODEL; }
    const int ntx = N >> 5;
    const int k0 = (tb / ntx) * 32;
    const int n0 = (tb % ntx) * 32;

    const int tx = threadIdx.x & 31;
    const int ty = threadIdx.x >> 5;
#pragma unroll
    for (int i = 0; i < 4; ++i)
        t[ty + 8 * i][tx] = W[(size_t)(k0 + ty + 8 * i) * N + n0 + tx];
    __syncthreads();
#pragma unroll
    for (int i = 0; i < 4; ++i)
        Wt[(size_t)(n0 + ty + 8 * i) * K + k0 + tx] =
            __float2bfloat16(t[tx][ty + 8 * i]);
}

// ----------------------------------------------------------- helpers
__device__ __forceinline__ void async16(const __hip_bfloat16* g, __hip_bfloat16* l)
{
    __builtin_amdgcn_global_load_lds(
        (const __attribute__((address_space(1))) void*)g,
        (__attribute__((address_space(3))) void*)l, 16, 0, 0);
}

__device__ __forceinline__ float gelu_exact(float v)
{
    return 0.5f * v * (1.0f + erff(v * 0.70710678118654752f));
}

__device__ __forceinline__ void swizzle_bxy(int& bx, int& by)
{
    const int nbx = gridDim.x;
    const int lin = blockIdx.y * nbx + blockIdx.x;
    const int stripe = 4 * nbx;
    const int s = lin / stripe;
    const int rem = lin - s * stripe;
    by = s * 4 + (rem & 3);
    bx = rem >> 2;
}

// ---------------- Round-8 core: 128x128 block, 64x64 wave, 4-deep, vmcnt(4)
__device__ __forceinline__ void gemm_pipeline_core(
    const __hip_bfloat16* __restrict__ A,
    const __hip_bfloat16* __restrict__ Bt,
    int K, int row0, int col0,
    int wm, int wn, int ln15, int lq,
    f32x4 (&acc)[4][4])
{
    __shared__ __align__(16) __hip_bfloat16 As0[4096], As1[4096],
                                            As2[4096], As3[4096];
    __shared__ __align__(16) __hip_bfloat16 Bs0[4096], Bs1[4096],
                                            Bs2[4096], Bs3[4096];
    __hip_bfloat16* const Ab[4] = {As0, As1, As2, As3};
    __hip_bfloat16* const Bb[4] = {Bs0, Bs1, Bs2, Bs3};

    const int tid  = threadIdx.x;
    const int wv   = tid >> 6;
    const int lane = tid & 63;
    const int sr = wv * 16 + (lane >> 2);
    const int sq = (lane & 3) * 8;

    auto stage = [&](int kt, __hip_bfloat16* as, __hip_bfloat16* bs) {
        const int k0 = kt * 32;
#pragma unroll
        for (int i = 0; i < 2; ++i) {
            const int r = i * 64 + sr;
            async16(A  + (size_t)(row0 + r) * K + k0 + sq, as + r * 32);
            async16(Bt + (size_t)(col0 + r) * K + k0 + sq, bs + r * 32);
        }
    };

#pragma unroll
    for (int i = 0; i < 4; ++i)
#pragma unroll
        for (int j = 0; j < 4; ++j) acc[i][j] = (f32x4){0.f, 0.f, 0.f, 0.f};

    stage(0, Ab[0], Bb[0]);
    stage(1, Ab[1], Bb[1]);

    const int nt = K >> 5;
    for (int t0 = 0; t0 < nt; t0 += 4) {
#pragma unroll
        for (int u = 0; u < 4; ++u) {
            const int t = t0 + u;
            if (t + 1 < nt) WAIT_VM4(); else WAIT_VM0();
            __builtin_amdgcn_s_barrier();
            const __hip_bfloat16* as = Ab[u];
            const __hip_bfloat16* bs = Bb[u];
            bf16x8 af[4], bfr[4];
#pragma unroll
            for (int mi = 0; mi < 4; ++mi)
                af[mi] = *(const bf16x8*)&as[(wm + mi * 16 + ln15) * 32 + lq * 8];
#pragma unroll
            for (int ni = 0; ni < 4; ++ni)
                bfr[ni] = *(const bf16x8*)&bs[(wn + ni * 16 + ln15) * 32 + lq * 8];
#pragma unroll
            for (int mi = 0; mi < 4; ++mi)
#pragma unroll
                for (int ni = 0; ni < 4; ++ni)
                    acc[mi][ni] = __builtin_amdgcn_mfma_f32_16x16x32_bf16(
                        af[mi], bfr[ni], acc[mi][ni], 0, 0, 0);
            if (t + 2 < nt) stage(t + 2, Ab[(u + 2) & 3], Bb[(u + 2) & 3]);
        }
    }
}

// ---------------- Round-9 wide core: 256x128 block, 128x64 wave tile,
// 2-deep LDS (48 KB), two raw barriers/iter, vmcnt(6). nt must be even.
__device__ __forceinline__ void gemm_pipeline_wide(
    const __hip_bfloat16* __restrict__ A,
    const __hip_bfloat16* __restrict__ Bt,
    int K, int row0, int col0,
    int wm, int wn, int ln15, int lq,
    f32x4 (&acc)[8][4])
{
    __shared__ __align__(16) __hip_bfloat16 As0[256 * 32], As1[256 * 32];
    __shared__ __align__(16) __hip_bfloat16 Bs0[128 * 32], Bs1[128 * 32];

    const int tid  = threadIdx.x;
    const int wv   = tid >> 6;
    const int lane = tid & 63;
    const int sr = wv * 16 + (lane >> 2);
    const int sq = (lane & 3) * 8;

    auto stage = [&](int kt, __hip_bfloat16* as, __hip_bfloat16* bs) {
        const int k0 = kt * 32;
#pragma unroll
        for (int i = 0; i < 4; ++i) {                 // A: 256 rows
            const int r = i * 64 + sr;
            async16(A + (size_t)(row0 + r) * K + k0 + sq, as + r * 32);
        }
#pragma unroll
        for (int i = 0; i < 2; ++i) {                 // B: 128 rows
            const int r = i * 64 + sr;
            async16(Bt + (size_t)(col0 + r) * K + k0 + sq, bs + r * 32);
        }
    };

#pragma unroll
    for (int i = 0; i < 8; ++i)
#pragma unroll
        for (int j = 0; j < 4; ++j) acc[i][j] = (f32x4){0.f, 0.f, 0.f, 0.f};

    stage(0, As0, Bs0);
    stage(1, As1, Bs1);

    const int nt = K >> 5;
    for (int t0 = 0; t0 < nt; t0 += 2) {
#pragma unroll
        for (int u = 0; u < 2; ++u) {
            const int t = t0 + u;
            if (t + 1 < nt) WAIT_VM6(); else WAIT_VM0();
            __builtin_amdgcn_s_barrier();             // stage(t) landed for all
            const __hip_bfloat16* as = u ? As1 : As0;
            const __hip_bfloat16* bs = u ? Bs1 : Bs0;
            bf16x8 af[8], bfr[4];
#pragma unroll
            for (int mi = 0; mi < 8; ++mi)
                af[mi] = *(const bf16x8*)&as[(wm + mi * 16 + ln15) * 32 + lq * 8];
#pragma unroll
            for (int ni = 0; ni < 4; ++ni)
                bfr[ni] = *(const bf16x8*)&bs[(wn + ni * 16 + ln15) * 32 + lq * 8];
#pragma unroll
            for (int mi = 0; mi < 8; ++mi)
#pragma unroll
                for (int ni = 0; ni < 4; ++ni)
                    acc[mi][ni] = __builtin_amdgcn_mfma_f32_16x16x32_bf16(
                        af[mi], bfr[ni], acc[mi][ni], 0, 0, 0);
            __builtin_amdgcn_s_barrier();             // all done reading buf
            if (t + 2 < nt) stage(t + 2, u ? As1 : As0, u ? Bs1 : Bs0);
        }
    }
}

// ---------------- 128x128 kernel (proj, fc2)
__global__ __launch_bounds__(256) void mfma_gemm_kernel(
    const __hip_bfloat16* __restrict__ A,   // [M,K]
    const __hip_bfloat16* __restrict__ Bt,  // [N,K]
    const float* __restrict__ bias,         // [N]
    const float* __restrict__ residual,     // [M,N] or null
    void* __restrict__ Cout,                // [M,N] fp32 or bf16
    int M, int N, int K, int act, int outBf16)
{
    int bx, by;
    swizzle_bxy(bx, by);
    const int tid  = threadIdx.x;
    const int wv   = tid >> 6;
    const int lane = tid & 63;
    const int ln15 = lane & 15;
    const int lq   = lane >> 4;
    const int wm   = (wv >> 1) * 64;
    const int wn   = (wv & 1) * 64;
    const int row0 = by * 128;
    const int col0 = bx * 128;

    f32x4 acc[4][4];
    gemm_pipeline_core(A, Bt, K, row0, col0, wm, wn, ln15, lq, acc);

#pragma unroll
    for (int mi = 0; mi < 4; ++mi) {
#pragma unroll
        for (int ni = 0; ni < 4; ++ni) {
            const int gc = col0 + wn + ni * 16 + ln15;
            const float bv = bias[gc];
#pragma unroll
            for (int r = 0; r < 4; ++r) {
                const int gr = row0 + wm + mi * 16 + lq * 4 + r;
                float v = acc[mi][ni][r] + bv;
                if (act == 1) v = gelu_exact(v);
                if (residual) v += residual[(size_t)gr * N + gc];
                if (outBf16)
                    ((__hip_bfloat16*)Cout)[(size_t)gr * N + gc] = __float2bfloat16(v);
                else
                    ((float*)Cout)[(size_t)gr * N + gc] = v;
            }
        }
    }
}

// ---------------- 256x128 wide kernel (fc1: gelu -> bf16 out)
__global__ __launch_bounds__(256, 2) void mfma_gemm_wide_kernel(
    const __hip_bfloat16* __restrict__ A,   // [M,K]
    const __hip_bfloat16* __restrict__ Bt,  // [N,K]
    const float* __restrict__ bias,         // [N]
    void* __restrict__ Cout,                // [M,N]
    int M, int N, int K, int act, int outBf16)
{
    int bx, by;
    swizzle_bxy(bx, by);
    const int tid  = threadIdx.x;
    const int wv   = tid >> 6;
    const int lane = tid & 63;
    const int ln15 = lane & 15;
    const int lq   = lane >> 4;
    const int wm   = (wv >> 1) * 128;   // wave rows: 0 / 128
    const int wn   = (wv & 1) * 64;     // wave cols: 0 / 64
    const int row0 = by * 256;
    const int col0 = bx * 128;

    f32x4 acc[8][4];
    gemm_pipeline_wide(A, Bt, K, row0, col0, wm, wn, ln15, lq, acc);

#pragma unroll
    for (int mi = 0; mi < 8; ++mi) {
#pragma unroll
        for (int ni = 0; ni < 4; ++ni) {
            const int gc = col0 + wn + ni * 16 + ln15;
            const float bv = bias[gc];
#pragma unroll
            for (int r = 0; r < 4; ++r) {
                const int gr = row0 + wm + mi * 16 + lq * 4 + r;
                float v = acc[mi][ni][r] + bv;
                if (act == 1) v = gelu_exact(v);
                if (outBf16)
                    ((__hip_bfloat16*)Cout)[(size_t)gr * N + gc] = __float2bfloat16(v);
                else
                    ((float*)Cout)[(size_t)gr * N + gc] = v;
            }
        }
    }
}

// ---------------- wide qkv kernel with routing epilogue
__global__ __launch_bounds__(256, 2) void mfma_qkv_kernel(
    const __hip_bfloat16* __restrict__ A,
    const __hip_bfloat16* __restrict__ Bt,
    const float* __restrict__ bias,
    __hip_bfloat16* __restrict__ Qb,
    __hip_bfloat16* __restrict__ Kb,
    __hip_bfloat16* __restrict__ Vtb)
{
    const int K = D_MODEL;
    int bx, by;
    swizzle_bxy(bx, by);
    const int tid  = threadIdx.x;
    const int wv   = tid >> 6;
    const int lane = tid & 63;
    const int ln15 = lane & 15;
    const int lq   = lane >> 4;
    const int wm   = (wv >> 1) * 128;
    const int wn   = (wv & 1) * 64;
    const int row0 = by * 256;
    const int col0 = bx * 128;

    f32x4 acc[8][4];
    gemm_pipeline_wide(A, Bt, K, row0, col0, wm, wn, ln15, lq, acc);

#pragma unroll
    for (int mi = 0; mi < 8; ++mi) {
        const int gr0 = row0 + wm + mi * 16 + lq * 4;   // + r
        const int bb  = gr0 >> 11;
        const int q0  = gr0 & 2047;
#pragma unroll
        for (int ni = 0; ni < 4; ++ni) {
            const int gc  = col0 + wn + ni * 16 + ln15;
            const float bv = bias[gc];
            const int sec = gc >> 10;            // 0:Q 1:K 2:V
            const int hd  = (gc & 1023) >> 6;
            const int d   = gc & 63;
            if (sec == 2) {
                unsigned short u[4];
#pragma unroll
                for (int r = 0; r < 4; ++r) {
                    __hip_bfloat16 e = __float2bfloat16(acc[mi][ni][r] + bv);
                    u[r] = *(unsigned short*)&e;
                }
                uint2 pk;
                pk.x = (unsigned int)u[0] | ((unsigned int)u[1] << 16);
                pk.y = (unsigned int)u[2] | ((unsigned int)u[3] << 16);
                *(uint2*)(Vtb + ((size_t)((bb * N_HEAD + hd) * D_HEAD + d)) * SEQ_T + q0) = pk;
            } else {
                __hip_bfloat16* dst = (sec == 0 ? Qb : Kb)
                    + ((size_t)((bb * N_HEAD + hd) * SEQ_T + q0)) * D_HEAD + d;
#pragma unroll
                for (int r = 0; r < 4; ++r)
                    dst[(size_t)r * D_HEAD] = __float2bfloat16(acc[mi][ni][r] + bv);
            }
        }
    }
}

// ------------------------------------------------- MFMA flash attention v2
#define ATQ 64
#define ATK 128
#define NQT (SEQ_T / ATQ)   // 32
#define KP  72
#define VP  136

__global__ __launch_bounds__(256) void mfma_attn_kernel(
    const __hip_bfloat16* __restrict__ Qb,
    const __hip_bfloat16* __restrict__ Kb,
    const __hip_bfloat16* __restrict__ Vtb,
    __hip_bfloat16* __restrict__ y)
{
    __shared__ __align__(16) __hip_bfloat16 Ks[ATK * KP];
    __shared__ __align__(16) __hip_bfloat16 Vts[D_HEAD * VP];
    __shared__ __align__(16) __hip_bfloat16 Ps[ATQ * VP];

    const int pair = blockIdx.x;
    const int h    = blockIdx.y;
    const int b    = blockIdx.z;
    const int tid  = threadIdx.x;
    const int wv   = tid >> 6;
    const int lane = tid & 63;
    const int ln15 = lane & 15;
    const int lq   = lane >> 4;

    const __hip_bfloat16* Qh = Qb  + (size_t)(b * N_HEAD + h) * SEQ_T * D_HEAD;
    const __hip_bfloat16* Kh = Kb  + (size_t)(b * N_HEAD + h) * SEQ_T * D_HEAD;
    const __hip_bfloat16* Vh = Vtb + (size_t)(b * N_HEAD + h) * D_HEAD * SEQ_T;
    const size_t bT = (size_t)b * SEQ_T;

#pragma unroll 1
    for (int half = 0; half < 2; ++half) {
        const int qt    = half == 0 ? pair : (NQT - 1 - pair);
        const int qbase = qt * ATQ;
        const int ntk   = (qt >> 1) + 1;
        const int qg    = qbase + wv * 16 + ln15;

        bf16x8 qf[2];
#pragma unroll
        for (int kc = 0; kc < 2; ++kc)
            qf[kc] = *(const bf16x8*)(Qh + (size_t)(qbase + wv * 16 + ln15) * D_HEAD
                                      + kc * 32 + lq * 8);

        f32x4 Oacc[4];
#pragma unroll
        for (int dn = 0; dn < 4; ++dn) Oacc[dn] = (f32x4){0.f, 0.f, 0.f, 0.f};
        float m_run = -INFINITY, l_run = 0.f;

        for (int t = 0; t < ntk; ++t) {
            const int kb = t * ATK;
            __syncthreads();
#pragma unroll
            for (int i = 0; i < 4; ++i) {
                const int ch = tid + i * 256;
                const int r = ch >> 3, c8 = (ch & 7) * 8;
                *(bf16x8*)&Ks[r * KP + c8] =
                    *(const bf16x8*)(Kh + (size_t)(kb + r) * D_HEAD + c8);
            }
#pragma unroll
            for (int i = 0; i < 4; ++i) {
                const int ch = tid + i * 256;
                const int r = ch >> 4, c8 = (ch & 15) * 8;
                *(bf16x8*)&Vts[r * VP + c8] =
                    *(const bf16x8*)(Vh + (size_t)r * SEQ_T + kb + c8);
            }
            __syncthreads();

            f32x4 st[8];
#pragma unroll
            for (int jf = 0; jf < 8; ++jf) st[jf] = (f32x4){0.f, 0.f, 0.f, 0.f};
#pragma unroll
            for (int jf = 0; jf < 8; ++jf) {
                const bf16x8 kf0 = *(const bf16x8*)&Ks[(jf * 16 + ln15) * KP + lq * 8];
                const bf16x8 kf1 = *(const bf16x8*)&Ks[(jf * 16 + ln15) * KP + 32 + lq * 8];
                st[jf] = __builtin_amdgcn_mfma_f32_16x16x32_bf16(kf0, qf[0], st[jf], 0, 0, 0);
                st[jf] = __builtin_amdgcn_mfma_f32_16x16x32_bf16(kf1, qf[1], st[jf], 0, 0, 0);
            }

            const bool last = (t == ntk - 1);
#pragma unroll
            for (int jf = 0; jf < 8; ++jf)
#pragma unroll
                for (int r = 0; r < 4; ++r) {
                    float v = st[jf][r] * 0.125f;
                    if (last && (kb + jf * 16 + lq * 4 + r) > qg) v = -INFINITY;
                    st[jf][r] = v;
                }

            float tmax = st[0][0];
#pragma unroll
            for (int jf = 0; jf < 8; ++jf)
#pragma unroll
                for (int r = 0; r < 4; ++r) tmax = fmaxf(tmax, st[jf][r]);
            tmax = fmaxf(tmax, __shfl_xor(tmax, 16));
            tmax = fmaxf(tmax, __shfl_xor(tmax, 32));
            const float mnew  = fmaxf(m_run, tmax);
            const float alpha = __expf(m_run - mnew);
            float psum = 0.f;
#pragma unroll
            for (int jf = 0; jf < 8; ++jf)
#pragma unroll
                for (int r = 0; r < 4; ++r) {
                    const float p = __expf(st[jf][r] - mnew);
                    st[jf][r] = p;
                    psum += p;
                }
            psum += __shfl_xor(psum, 16);
            psum += __shfl_xor(psum, 32);
            l_run = alpha * l_run + psum;
            m_run = mnew;

            float a4[4];
#pragma unroll
            for (int r = 0; r < 4; ++r) a4[r] = __shfl(alpha, lq * 4 + r);
#pragma unroll
            for (int dn = 0; dn < 4; ++dn)
#pragma unroll
                for (int r = 0; r < 4; ++r) Oacc[dn][r] *= a4[r];

#pragma unroll
            for (int jf = 0; jf < 8; ++jf) {
                __hip_bfloat162 p01 = __float22bfloat162_rn(make_float2(st[jf][0], st[jf][1]));
                __hip_bfloat162 p23 = __float22bfloat162_rn(make_float2(st[jf][2], st[jf][3]));
                uint2 pk;
                pk.x = *(unsigned int*)&p01;
                pk.y = *(unsigned int*)&p23;
                *(uint2*)&Ps[(wv * 16 + ln15) * VP + jf * 16 + lq * 4] = pk;
            }

            bf16x8 pf[4];
#pragma unroll
            for (int jc = 0; jc < 4; ++jc)
                pf[jc] = *(const bf16x8*)&Ps[(wv * 16 + ln15) * VP + jc * 32 + lq * 8];
#pragma unroll
            for (int dn = 0; dn < 4; ++dn) {
#pragma unroll
                for (int jc = 0; jc < 4; ++jc) {
                    const bf16x8 vf = *(const bf16x8*)&Vts[(dn * 16 + ln15) * VP + jc * 32 + lq * 8];
                    Oacc[dn] = __builtin_amdgcn_mfma_f32_16x16x32_bf16(
                        pf[jc], vf, Oacc[dn], 0, 0, 0);
                }
            }
        }

        float il[4];
#pragma unroll
        for (int r = 0; r < 4; ++r) il[r] = 1.0f / __shfl(l_run, lq * 4 + r);
#pragma unroll
        for (int dn = 0; dn < 4; ++dn)
#pragma unroll
            for (int r = 0; r < 4; ++r)
                Ps[(wv * 16 + lq * 4 + r) * VP + dn * 16 + ln15] =
                    __float2bfloat16(Oacc[dn][r] * il[r]);
        const int r2 = lane >> 3, c8 = (lane & 7) * 8;
#pragma unroll
        for (int i = 0; i < 2; ++i) {
            const int row = wv * 16 + r2 + 8 * i;
            const bf16x8 val = *(const bf16x8*)&Ps[row * VP + c8];
            *(bf16x8*)(y + (bT + qbase + row) * D_MODEL + h * D_HEAD + c8) = val;
        }
    }
}

// ------------------------------------------------------------------ launch
extern "C" void kernel_launch(void* const* d_in, const int* in_sizes, int n_in,
                              void* d_out, int out_size, void* d_ws, size_t ws_size,
                              hipStream_t stream)
{
    const float* x      = (const float*)d_in[0];
    const float* ln1_w  = (const float*)d_in[1];
    const float* ln1_b  = (const float*)d_in[2];
    const float* attn_w = (const float*)d_in[3];
    const float* attn_b = (const float*)d_in[4];
    const float* proj_w = (const float*)d_in[5];
    const float* proj_b = (const float*)d_in[6];
    const float* ln2_w  = (const float*)d_in[7];
    const float* ln2_b  = (const float*)d_in[8];
    const float* fc_w   = (const float*)d_in[9];
    const float* fc_b   = (const float*)d_in[10];
    const float* fc2_w  = (const float*)d_in[11];
    const float* fc2_b  = (const float*)d_in[12];
    float* out = (float*)d_out;

    char* ws = (char*)d_ws;
    __hip_bfloat16* Qb      = (__hip_bfloat16*)(ws);
    __hip_bfloat16* Kb      = (__hip_bfloat16*)(ws + (size_t)8  * 1024 * 1024);
    __hip_bfloat16* Vtb     = (__hip_bfloat16*)(ws + (size_t)16 * 1024 * 1024);
    __hip_bfloat16* h_bf    = (__hip_bfloat16*)(ws);
    __hip_bfloat16* ln_buf  = (__hip_bfloat16*)(ws + (size_t)32 * 1024 * 1024);
    __hip_bfloat16* y_buf   = (__hip_bfloat16*)(ws + (size_t)40 * 1024 * 1024);
    float*          xmid    = (float*)(ws + (size_t)48 * 1024 * 1024);
    __hip_bfloat16* attn_wt = (__hip_bfloat16*)(ws + (size_t)64 * 1024 * 1024);
    __hip_bfloat16* proj_wt = (__hip_bfloat16*)(ws + (size_t)70 * 1024 * 1024);
    __hip_bfloat16* fc_wt   = (__hip_bfloat16*)(ws + (size_t)72 * 1024 * 1024);
    __hip_bfloat16* fc2_wt  = (__hip_bfloat16*)(ws + (size_t)80 * 1024 * 1024);

    dim3 blk256(256);

    // 0. all weight transposes in one launch (fp32 [K,N] -> bf16 [N,K])
    transpose_all_kernel<<<dim3(12288), blk256, 0, stream>>>(
        attn_w, proj_w, fc_w, fc2_w, attn_wt, proj_wt, fc_wt, fc2_wt);

    // 1. ln1(x) -> ln_buf (bf16)
    ln_kernel<<<dim3(NROWS), blk256, 0, stream>>>(x, ln1_w, ln1_b, ln_buf, D_MODEL);

    // 2. qkv GEMM (wide 256x128) -> Qb/Kb/Vtb
    mfma_qkv_kernel<<<dim3(C3 / 128, NROWS / 256), blk256, 0, stream>>>(
        ln_buf, attn_wt, attn_b, Qb, Kb, Vtb);

    // 3. MFMA flash attention -> y_buf (bf16)
    mfma_attn_kernel<<<dim3(NQT / 2, N_HEAD, BATCH), blk256, 0, stream>>>(
        Qb, Kb, Vtb, y_buf);

    // 4. xmid = x + y_buf @ proj_w + proj_b  (fp32, 128x128 kernel)
    mfma_gemm_kernel<<<dim3(D_MODEL / 128, NROWS / 128), blk256, 0, stream>>>(
        y_buf, proj_wt, proj_b, x, xmid, NROWS, D_MODEL, D_MODEL, 0, 0);

    // 5. ln2(xmid) -> ln_buf (bf16)
    ln_kernel<<<dim3(NROWS), blk256, 0, stream>>>(xmid, ln2_w, ln2_b, ln_buf, D_MODEL);

    // 6. h = gelu(ln_buf @ fc_w + fc_b) -> bf16 (wide 256x128)
    mfma_gemm_wide_kernel<<<dim3(D_FF / 128, NROWS / 256), blk256, 0, stream>>>(
        ln_buf, fc_wt, fc_b, h_bf, NROWS, D_FF, D_MODEL, 1, 1);

    // 7. out = xmid + h @ fc2_w + fc2_b  (fp32, 128x128 kernel)
    mfma_gemm_kernel<<<dim3(D_MODEL / 128, NROWS / 128), blk256, 0, stream>>>(
        h_bf, fc2_wt, fc2_b, xmid, out, NROWS, D_MODEL, D_FF, 0, 0);
}